// Round 1
// baseline (2128.495 us; speedup 1.0000x reference)
//
#include <hip/hip_runtime.h>
#include <math.h>

// ---------------------------------------------------------------------------
// WavLM self-attention, fp32 baseline.
//   B=8 S=1024 H=16 D=64 E=1024, NUM_BUCKETS=32, MAX_DIST=128, SCALING=0.125
// Workspace layout (floats):
//   q_ws   [B*H*S*D]  @ 0          (8M)
//   k_ws   [B*H*S*D]  @ 8388608
//   v_ws   [B*H*S*D]  @ 16777216
//   ctx    [B*S*E]    @ 25165824
//   gate   [B*H*S]    @ 33554432   (128K)
//   btab   [H*2048]   @ 33685504   (32K)
// Total ~129 MB of d_ws.
// ---------------------------------------------------------------------------

#define LDSP(p) ((__attribute__((address_space(3))) void*)(p))
#define GLBP(p) ((const __attribute__((address_space(1))) void*)(p))

__device__ __forceinline__ void async_ld16(const float* src, float* dst) {
  // dst must be wave-uniform; HW writes lane i at dst + i*16B.
  __builtin_amdgcn_global_load_lds(GLBP(src), LDSP(dst), 16, 0, 0);
}

// ---------------------------------------------------------------------------
// Kernel 1: relative-position bias table. btab[h][idx] for idx = rel+1023.
// Double math to match numpy's float64 bucket computation exactly.
// ---------------------------------------------------------------------------
__global__ void prep_btab(const float* __restrict__ rel_embed,
                          float* __restrict__ btab) {
  const int idx = blockIdx.x * 256 + threadIdx.x;
  if (idx >= 2047) return;
  const int rel = idx - 1023;              // rel = k - q
  int bucket = (rel > 0) ? 16 : 0;
  const int rp = rel < 0 ? -rel : rel;
  if (rp < 8) {
    bucket += rp;
  } else {
    const double lv = log((double)rp / 8.0) / log(16.0) * 8.0;
    int large = 8 + (int)lv;
    bucket += (large < 15) ? large : 15;
  }
  #pragma unroll
  for (int h = 0; h < 16; ++h)
    btab[h * 2048 + idx] = rel_embed[bucket * 16 + h];
}

// ---------------------------------------------------------------------------
// Kernel 2: gate[b,h,s] = ga*(gb*gru_const[h]-1)+2,
//   ga = sigmoid(x_head . sum(gru_w[:,0:4]) + sum(gru_b[0:4])), gb likewise 4:8.
// One block per (b,s); 256 threads = 16 heads x 16 partial lanes.
// ---------------------------------------------------------------------------
__global__ __launch_bounds__(256) void gate_kernel(
    const float* __restrict__ x, const float* __restrict__ gw,
    const float* __restrict__ gb, const float* __restrict__ gcst,
    float* __restrict__ gate_ws) {
  __shared__ __align__(16) float xr[1024];
  const int bs = blockIdx.x;
  const int t  = threadIdx.x;
  *(float4*)&xr[t * 4] = *(const float4*)&x[(size_t)bs * 1024 + t * 4];
  __syncthreads();
  const int h = t >> 4, i = t & 15;
  float pa = 0.f, pb = 0.f;
  #pragma unroll
  for (int j = 0; j < 4; ++j) {
    const int d = i * 4 + j;
    const float xv = xr[h * 64 + d];
    const float* wr = &gw[d * 8];
    pa += xv * (wr[0] + wr[1] + wr[2] + wr[3]);
    pb += xv * (wr[4] + wr[5] + wr[6] + wr[7]);
  }
  #pragma unroll
  for (int msk = 1; msk <= 8; msk <<= 1) {
    pa += __shfl_xor(pa, msk);
    pb += __shfl_xor(pb, msk);
  }
  if (i == 0) {
    const float ba = gb[0] + gb[1] + gb[2] + gb[3];
    const float bb = gb[4] + gb[5] + gb[6] + gb[7];
    const float ga  = 1.f / (1.f + __expf(-(pa + ba)));
    const float gbv = 1.f / (1.f + __expf(-(pb + bb)));
    const float gv  = ga * (gbv * gcst[h] - 1.f) + 2.f;
    const int b = bs >> 10, s = bs & 1023;
    gate_ws[(b * 16 + h) * 1024 + s] = gv;
  }
}

// ---------------------------------------------------------------------------
// Kernel 3: fp32 GEMM  C = A(MxK=..x1024) @ B(1024x1024 slice) + bias.
// BM=BN=128, BK=32, 256 threads, 8x8 per thread.
// Staging via global_load_lds (16B) with pre-swizzled global sources so LDS
// stays linear but fragment ds_read_b128s are conflict-free (A) / 2-way (B).
//   A LDS [m][k], chunk swizzle: c_phys = c ^ ((row>>3)&3)   (c = k/4, 0..7)
//   B LDS [k][n], chunk swizzle: c_phys = c ^ ((c>>3)&3)     (c = n/4, 0..31)
// scatter=0: C[m][n] row-major (ld 1024).  scatter=1: C[((b*16+h)*1024+s)*64+d].
// ---------------------------------------------------------------------------
__global__ __launch_bounds__(256) void gemm128(
    const float* __restrict__ A, const float* __restrict__ B,
    const float* __restrict__ bias, float* __restrict__ C, const int scatter) {
  __shared__ __align__(16) float As_s[128 * 32];   // 16 KB
  __shared__ __align__(16) float Bs_s[32 * 128];   // 16 KB
  const int t  = threadIdx.x;
  const int w  = t >> 6, l = t & 63;
  const int tx = t & 15, ty = t >> 4;
  const int m0 = blockIdx.x * 128;
  const int n0 = blockIdx.y * 128;

  const float* aptr[4];
  const float* bptr[4];
  float* adst[4];
  float* bdst[4];
  #pragma unroll
  for (int i = 0; i < 4; ++i) {
    const int p  = (w * 4 + i) * 64 + l;        // phys 16B-chunk index
    const int ar = p >> 3;                       // A: 8 chunks per row
    const int ac = (p & 7) ^ ((ar >> 3) & 3);    // source chunk for this slot
    aptr[i] = A + (size_t)(m0 + ar) * 1024 + ac * 4;
    adst[i] = &As_s[(w * 4 + i) * 256];          // wave-uniform base
    const int bk = p >> 5;                       // B: 32 chunks per row
    const int bc = p & 31;
    const int bcs = bc ^ ((bc >> 3) & 3);
    bptr[i] = B + (size_t)bk * 1024 + n0 + bcs * 4;
    bdst[i] = &Bs_s[(w * 4 + i) * 256];
  }

  float acc[8][8];
  #pragma unroll
  for (int j = 0; j < 8; ++j)
    #pragma unroll
    for (int i = 0; i < 8; ++i) acc[j][i] = 0.f;

  const int ca   = ty & 3;
  const int arow = ty * 256;  // (ty*8 rows) * 32 floats
  const int c0o  = (((tx * 2)     ^ ((tx >> 2) & 3)) << 2);
  const int c1o  = (((tx * 2 + 1) ^ ((tx >> 2) & 3)) << 2);

  for (int k0 = 0; k0 < 1024; k0 += 32) {
    #pragma unroll
    for (int i = 0; i < 4; ++i) {
      async_ld16(aptr[i], adst[i]);
      async_ld16(bptr[i], bdst[i]);
      aptr[i] += 32;
      bptr[i] += 32 * 1024;
    }
    __syncthreads();   // vmcnt(0) drain -> tiles visible
    #pragma unroll
    for (int kc = 0; kc < 8; ++kc) {
      float4 a4[8];
      #pragma unroll
      for (int j = 0; j < 8; ++j)
        a4[j] = *(const float4*)&As_s[arow + j * 32 + ((kc ^ ca) << 2)];
      float4 b40[4], b41[4];
      #pragma unroll
      for (int kk = 0; kk < 4; ++kk) {
        const int kb = (kc * 4 + kk) * 128;
        b40[kk] = *(const float4*)&Bs_s[kb + c0o];
        b41[kk] = *(const float4*)&Bs_s[kb + c1o];
      }
      #pragma unroll
      for (int kk = 0; kk < 4; ++kk) {
        #pragma unroll
        for (int j = 0; j < 8; ++j) {
          const float av = (&a4[j].x)[kk];
          acc[j][0] += av * b40[kk].x;
          acc[j][1] += av * b40[kk].y;
          acc[j][2] += av * b40[kk].z;
          acc[j][3] += av * b40[kk].w;
          acc[j][4] += av * b41[kk].x;
          acc[j][5] += av * b41[kk].y;
          acc[j][6] += av * b41[kk].z;
          acc[j][7] += av * b41[kk].w;
        }
      }
    }
    __syncthreads();   // compute done before next-tile staging
  }

  const int nb = n0 + tx * 8;
  float bvv[8];
  *(float4*)&bvv[0] = *(const float4*)&bias[nb];
  *(float4*)&bvv[4] = *(const float4*)&bias[nb + 4];
  if (scatter == 0) {
    #pragma unroll
    for (int j = 0; j < 8; ++j) {
      const int mm = m0 + ty * 8 + j;
      float4 o0, o1;
      o0.x = acc[j][0] + bvv[0]; o0.y = acc[j][1] + bvv[1];
      o0.z = acc[j][2] + bvv[2]; o0.w = acc[j][3] + bvv[3];
      o1.x = acc[j][4] + bvv[4]; o1.y = acc[j][5] + bvv[5];
      o1.z = acc[j][6] + bvv[6]; o1.w = acc[j][7] + bvv[7];
      *(float4*)&C[(size_t)mm * 1024 + nb]     = o0;
      *(float4*)&C[(size_t)mm * 1024 + nb + 4] = o1;
    }
  } else {
    const int h = nb >> 6, d = nb & 63;
    #pragma unroll
    for (int j = 0; j < 8; ++j) {
      const int mm = m0 + ty * 8 + j;
      const int b = mm >> 10, s = mm & 1023;
      float* dst = C + (size_t)((b * 16 + h) * 1024 + s) * 64 + d;
      float4 o0, o1;
      o0.x = acc[j][0] + bvv[0]; o0.y = acc[j][1] + bvv[1];
      o0.z = acc[j][2] + bvv[2]; o0.w = acc[j][3] + bvv[3];
      o1.x = acc[j][4] + bvv[4]; o1.y = acc[j][5] + bvv[5];
      o1.z = acc[j][6] + bvv[6]; o1.w = acc[j][7] + bvv[7];
      *(float4*)dst       = o0;
      *(float4*)(dst + 4) = o1;
    }
  }
}

// ---------------------------------------------------------------------------
// Kernel 4: flash attention (fp32) with gated rel-pos bias.
// Block = 256 threads, 32 q-rows; K/V tiles of 64 staged via global_load_lds.
// K source-swizzled (c_phys = c ^ ((kr>>1)&7)) so score-phase column reads are
// 4-way instead of 32-way. Thread (rowblk=t>>5, colblk=t&31) owns 4 rows and
// 2 cols (scores) / 2 d (PV) -> m/l shfl-reduced over 32-lane row groups.
// ---------------------------------------------------------------------------
__global__ __launch_bounds__(256) void attn_kernel(
    const float* __restrict__ q_ws, const float* __restrict__ k_ws,
    const float* __restrict__ v_ws, const float* __restrict__ gate_ws,
    const float* __restrict__ btab, float* __restrict__ ctx) {
  __shared__ __align__(16) float Qs[32 * 64];   // 8 KB, linear [r][d]
  __shared__ __align__(16) float Ks[64 * 64];   // 16 KB, chunk-swizzled
  __shared__ __align__(16) float Vs[64 * 64];   // 16 KB, linear [kr][d]
  __shared__ __align__(16) float Ps[32 * 64];   // 8 KB, softmax weights
  __shared__ float gates[32];

  const int t  = threadIdx.x;
  const int w  = t >> 6, l = t & 63;
  const int bh = blockIdx.x;             // b*16+h
  const int h  = bh & 15;
  const int q0 = blockIdx.y * 32;
  const int rowblk = t >> 5;             // 0..7
  const int colblk = t & 31;             // 0..31
  const int r0 = rowblk * 4;

  const float* qbase = q_ws + ((size_t)bh * 1024 + q0) * 64;
  const float* kbase = k_ws + (size_t)bh * 65536;
  const float* vbase = v_ws + (size_t)bh * 65536;
  const float* brow  = btab + h * 2048 + 1023;   // index by (kcol - qrow)

  #pragma unroll
  for (int i = 0; i < 2; ++i) {          // stage Q: 2048 floats, linear
    const int p = (w * 2 + i) * 64 + l;
    async_ld16(qbase + p * 4, &Qs[(w * 2 + i) * 256]);
  }
  if (t < 32) gates[t] = gate_ws[bh * 1024 + q0 + t];

  float m[4], lsum[4], acc[4][2];
  #pragma unroll
  for (int j = 0; j < 4; ++j) {
    m[j] = -1e30f; lsum[j] = 0.f; acc[j][0] = 0.f; acc[j][1] = 0.f;
  }

  const int g   = colblk & 7;            // K-read swizzle key (same for both rows)
  const int kr0 = colblk * 2;
  const int d0  = colblk * 2;

  for (int kt = 0; kt < 16; ++kt) {
    __syncthreads();                     // prev PV done / initial Q landed
    const float* ksrc = kbase + kt * 4096;
    const float* vsrc = vbase + kt * 4096;
    #pragma unroll
    for (int i = 0; i < 4; ++i) {        // stage K (swizzled src) + V (linear)
      const int p  = (w * 4 + i) * 64 + l;
      const int kr = p >> 4;
      const int csrc = (p & 15) ^ ((kr >> 1) & 7);
      async_ld16(ksrc + kr * 64 + csrc * 4, &Ks[(w * 4 + i) * 256]);
      async_ld16(vsrc + p * 4,              &Vs[(w * 4 + i) * 256]);
    }
    __syncthreads();                     // tiles visible

    // ---- scores: s[4 rows][2 cols] over D=64 -----------------------------
    float s[4][2];
    #pragma unroll
    for (int j = 0; j < 4; ++j) { s[j][0] = 0.f; s[j][1] = 0.f; }
    const float* K0 = &Ks[kr0 * 64];
    #pragma unroll
    for (int dc = 0; dc < 16; ++dc) {
      const int off = ((dc ^ g) << 2);
      const float4 k0 = *(const float4*)(K0 + off);
      const float4 k1 = *(const float4*)(K0 + 64 + off);
      #pragma unroll
      for (int j = 0; j < 4; ++j) {
        const float4 q4 = *(const float4*)&Qs[(r0 + j) * 64 + (dc << 2)];
        s[j][0] += q4.x * k0.x + q4.y * k0.y + q4.z * k0.z + q4.w * k0.w;
        s[j][1] += q4.x * k1.x + q4.y * k1.y + q4.z * k1.z + q4.w * k1.w;
      }
    }
    // ---- scale + gated bias ---------------------------------------------
    float sc[4][2];
    #pragma unroll
    for (int j = 0; j < 4; ++j) {
      const int qrow = q0 + r0 + j;
      const float gt = gates[r0 + j];
      #pragma unroll
      for (int c = 0; c < 2; ++c) {
        const int kcol = kt * 64 + kr0 + c;
        sc[j][c] = 0.125f * s[j][c] + gt * brow[kcol - qrow];
      }
    }
    // ---- online softmax (reduce across the 32 col lanes) -----------------
    #pragma unroll
    for (int j = 0; j < 4; ++j) {
      float tm = fmaxf(sc[j][0], sc[j][1]);
      #pragma unroll
      for (int msk = 1; msk <= 16; msk <<= 1) tm = fmaxf(tm, __shfl_xor(tm, msk));
      const float mnew  = fmaxf(m[j], tm);
      const float scale = __expf(m[j] - mnew);
      m[j] = mnew;
      const float p0 = __expf(sc[j][0] - mnew);
      const float p1 = __expf(sc[j][1] - mnew);
      Ps[(r0 + j) * 64 + kr0]     = p0;
      Ps[(r0 + j) * 64 + kr0 + 1] = p1;
      float ls = p0 + p1;
      #pragma unroll
      for (int msk = 1; msk <= 16; msk <<= 1) ls += __shfl_xor(ls, msk);
      lsum[j] = lsum[j] * scale + ls;
      acc[j][0] *= scale;
      acc[j][1] *= scale;
    }
    __syncthreads();                     // Ps visible

    // ---- PV: acc[4 rows][2 d] += P(32x64) @ V(64x64) ---------------------
    #pragma unroll
    for (int kc = 0; kc < 16; ++kc) {
      float4 w4[4];
      #pragma unroll
      for (int j = 0; j < 4; ++j)
        w4[j] = *(const float4*)&Ps[(r0 + j) * 64 + (kc << 2)];
      #pragma unroll
      for (int kk = 0; kk < 4; ++kk) {
        const float2 v2 = *(const float2*)&Vs[(kc * 4 + kk) * 64 + d0];
        #pragma unroll
        for (int j = 0; j < 4; ++j) {
          const float wv = (&w4[j].x)[kk];
          acc[j][0] += wv * v2.x;
          acc[j][1] += wv * v2.y;
        }
      }
    }
  }

  // ---- epilogue: ctx[(b*1024+s)*1024 + h*64 + d] -------------------------
  const int b = bh >> 4;
  #pragma unroll
  for (int j = 0; j < 4; ++j) {
    const float inv = 1.f / lsum[j];
    const int srow = q0 + r0 + j;
    float* dst = ctx + ((size_t)(b * 1024 + srow) * 16 + h) * 64 + d0;
    *(float2*)dst = make_float2(acc[j][0] * inv, acc[j][1] * inv);
  }
}

// ---------------------------------------------------------------------------
extern "C" void kernel_launch(void* const* d_in, const int* in_sizes, int n_in,
                              void* d_out, int out_size, void* d_ws, size_t ws_size,
                              hipStream_t stream) {
  const float* x    = (const float*)d_in[0];
  const float* Wq   = (const float*)d_in[1];
  const float* bq   = (const float*)d_in[2];
  const float* Wk   = (const float*)d_in[3];
  const float* bk   = (const float*)d_in[4];
  const float* Wv   = (const float*)d_in[5];
  const float* bv   = (const float*)d_in[6];
  const float* Wo   = (const float*)d_in[7];
  const float* bo   = (const float*)d_in[8];
  const float* rel  = (const float*)d_in[9];
  const float* gw   = (const float*)d_in[10];
  const float* gb   = (const float*)d_in[11];
  const float* gcst = (const float*)d_in[12];
  float* out = (float*)d_out;

  float* ws    = (float*)d_ws;
  float* q_ws  = ws;
  float* k_ws  = ws + 8388608;
  float* v_ws  = ws + 16777216;
  float* ctx   = ws + 25165824;
  float* gate  = ws + 33554432;
  float* btab  = ws + 33685504;

  prep_btab  <<<dim3(8),       256, 0, stream>>>(rel, btab);
  gate_kernel<<<dim3(8192),    256, 0, stream>>>(x, gw, gb, gcst, gate);
  gemm128    <<<dim3(64, 8),   256, 0, stream>>>(x, Wq, bq, q_ws, 1);
  gemm128    <<<dim3(64, 8),   256, 0, stream>>>(x, Wk, bk, k_ws, 1);
  gemm128    <<<dim3(64, 8),   256, 0, stream>>>(x, Wv, bv, v_ws, 1);
  attn_kernel<<<dim3(128, 32), 256, 0, stream>>>(q_ws, k_ws, v_ws, gate, btab, ctx);
  gemm128    <<<dim3(64, 8),   256, 0, stream>>>(ctx, Wo, bo, out, 0);
}

// Round 2
// 385.554 us; speedup vs baseline: 5.5206x; 5.5206x over previous
//
#include <hip/hip_runtime.h>
#include <hip/hip_bf16.h>
#include <math.h>

// ---------------------------------------------------------------------------
// WavLM self-attention, bf16-MFMA version.
//   B=8 S=1024 H=16 D=64 E=1024, SCALING=0.125
// All matmuls via v_mfma_f32_16x16x32_bf16 (fp32 accumulate).
// Workspace (bytes):
//   x_bf  [8M bf16]          @ 0
//   wtq/wtk/wtv/wto [1M bf16] @ 16M,18M,20M,22M   (W^T: [n][k])
//   q_ws  [8M bf16, (bh,s,d)] @ 25165824
//   k_ws  [8M bf16, (bh,s,d)] @ 41943040
//   vt_ws [8M bf16, (bh,d,s)] @ 58720256
//   ctx   [8M bf16, (b,s,e)]  @ 75497472
//   gate  [128K f32]          @ 92274688
//   btab  [32K f32]           @ 92798976
// ---------------------------------------------------------------------------

typedef __attribute__((ext_vector_type(8))) short short8;
typedef __attribute__((ext_vector_type(4))) float f32x4;

#define LDSP(p) ((__attribute__((address_space(3))) void*)(p))
#define GLBP(p) ((const __attribute__((address_space(1))) void*)(p))

__device__ __forceinline__ void async_ld16(const void* src, void* dst) {
  // LDS dst wave-uniform; HW writes lane i at dst + i*16B. Src is per-lane.
  __builtin_amdgcn_global_load_lds(GLBP(src), LDSP(dst), 16, 0, 0);
}
__device__ __forceinline__ unsigned short f2bf(float f) {
  __hip_bfloat16 h = __float2bfloat16(f);
  return __builtin_bit_cast(unsigned short, h);
}

// ---------------------------------------------------------------------------
// relative-position bias table. btab[h][rel+1023], double math = numpy exact.
// ---------------------------------------------------------------------------
__global__ void prep_btab(const float* __restrict__ rel_embed,
                          float* __restrict__ btab) {
  const int idx = blockIdx.x * 256 + threadIdx.x;
  if (idx >= 2047) return;
  const int rel = idx - 1023;
  int bucket = (rel > 0) ? 16 : 0;
  const int rp = rel < 0 ? -rel : rel;
  if (rp < 8) {
    bucket += rp;
  } else {
    const double lv = log((double)rp / 8.0) / log(16.0) * 8.0;
    int large = 8 + (int)lv;
    bucket += (large < 15) ? large : 15;
  }
  #pragma unroll
  for (int h = 0; h < 16; ++h)
    btab[h * 2048 + idx] = rel_embed[bucket * 16 + h];
}

// ---------------------------------------------------------------------------
// gate[b,h,s] (fp32 path, unchanged from validated round-1 kernel)
// ---------------------------------------------------------------------------
__global__ __launch_bounds__(256) void gate_kernel(
    const float* __restrict__ x, const float* __restrict__ gw,
    const float* __restrict__ gb, const float* __restrict__ gcst,
    float* __restrict__ gate_ws) {
  __shared__ __align__(16) float xr[1024];
  const int bs = blockIdx.x;
  const int t  = threadIdx.x;
  *(float4*)&xr[t * 4] = *(const float4*)&x[(size_t)bs * 1024 + t * 4];
  __syncthreads();
  const int h = t >> 4, i = t & 15;
  float pa = 0.f, pb = 0.f;
  #pragma unroll
  for (int j = 0; j < 4; ++j) {
    const int d = i * 4 + j;
    const float xv = xr[h * 64 + d];
    const float* wr = &gw[d * 8];
    pa += xv * (wr[0] + wr[1] + wr[2] + wr[3]);
    pb += xv * (wr[4] + wr[5] + wr[6] + wr[7]);
  }
  #pragma unroll
  for (int msk = 1; msk <= 8; msk <<= 1) {
    pa += __shfl_xor(pa, msk);
    pb += __shfl_xor(pb, msk);
  }
  if (i == 0) {
    const float ba = gb[0] + gb[1] + gb[2] + gb[3];
    const float bb = gb[4] + gb[5] + gb[6] + gb[7];
    const float ga  = 1.f / (1.f + __expf(-(pa + ba)));
    const float gbv = 1.f / (1.f + __expf(-(pb + bb)));
    const float gv  = ga * (gbv * gcst[h] - 1.f) + 2.f;
    const int b = bs >> 10, s = bs & 1023;
    gate_ws[(b * 16 + h) * 1024 + s] = gv;
  }
}

// ---------------------------------------------------------------------------
// x fp32 -> bf16
// ---------------------------------------------------------------------------
__global__ __launch_bounds__(256) void cvt_x(const float* __restrict__ x,
                                             unsigned short* __restrict__ xb) {
  const int i = (blockIdx.x * 256 + threadIdx.x) * 4;
  const float4 v = *(const float4*)&x[i];
  ushort4 o;
  o.x = f2bf(v.x); o.y = f2bf(v.y); o.z = f2bf(v.z); o.w = f2bf(v.w);
  *(ushort4*)&xb[i] = o;
}

// ---------------------------------------------------------------------------
// W[k][n] fp32 (1024x1024) -> Wt[n][k] bf16
// ---------------------------------------------------------------------------
__global__ __launch_bounds__(256) void transW(const float* __restrict__ W,
                                              unsigned short* __restrict__ Wt) {
  __shared__ __align__(16) float tile[64][68];
  const int n0 = blockIdx.x * 64, k0 = blockIdx.y * 64;
  const int c = (threadIdx.x & 15) * 4, r = threadIdx.x >> 4;  // r 0..15
  #pragma unroll
  for (int i = 0; i < 4; ++i)
    *(float4*)&tile[r + i * 16][c] =
        *(const float4*)&W[(size_t)(k0 + r + i * 16) * 1024 + n0 + c];
  __syncthreads();
  #pragma unroll
  for (int i = 0; i < 4; ++i) {
    const int n = r + i * 16;
    ushort4 o;
    o.x = f2bf(tile[c + 0][n]); o.y = f2bf(tile[c + 1][n]);
    o.z = f2bf(tile[c + 2][n]); o.w = f2bf(tile[c + 3][n]);
    *(ushort4*)&Wt[(size_t)(n0 + n) * 1024 + k0 + c] = o;
  }
}

// ---------------------------------------------------------------------------
// bf16 MFMA GEMM: C = A(Mx1024) @ Bt^T + bias.  A[m][k], Bt[n][k] bf16.
// BM=BN=128, BK=64, 256 threads (4 waves), wave -> 64x64 out (4x4 frags).
// LDS linear rows of 64 bf16 (8x16B chunks), source-swizzled c^(r&7) so
// frag ds_read_b128 (row=lr, chunk=lg) is conflict-free (rule 21 involution).
// mode 0: C fp32 [m][1024].  mode 1: bf16 (bh,s,d).  mode 2: bf16 (bh,d,s).
// ---------------------------------------------------------------------------
__global__ __launch_bounds__(256) void gemm_bf(
    const unsigned short* __restrict__ A, const unsigned short* __restrict__ Bt,
    const float* __restrict__ bias, void* __restrict__ Cv, const int mode) {
  __shared__ __align__(16) unsigned short As[128 * 64];  // 16 KB
  __shared__ __align__(16) unsigned short Bs[128 * 64];  // 16 KB
  const int t = threadIdx.x, w = t >> 6, l = t & 63;
  const int lr = l & 15, lg = l >> 4;
  const int wr = w >> 1, wc = w & 1;
  const int m0 = blockIdx.x * 128, n0 = blockIdx.y * 128;

  const unsigned short* asrc[4];
  const unsigned short* bsrc[4];
  unsigned short* adst[4];
  unsigned short* bdst[4];
  #pragma unroll
  for (int i = 0; i < 4; ++i) {
    const int p = (w * 4 + i) * 64 + l, r = p >> 3, c = p & 7;
    const int cs = c ^ (r & 7);
    asrc[i] = A + (size_t)(m0 + r) * 1024 + cs * 8;
    bsrc[i] = Bt + (size_t)(n0 + r) * 1024 + cs * 8;
    adst[i] = &As[(w * 4 + i) * 512];
    bdst[i] = &Bs[(w * 4 + i) * 512];
  }

  f32x4 acc[4][4];
  #pragma unroll
  for (int mt = 0; mt < 4; ++mt)
    #pragma unroll
    for (int nt = 0; nt < 4; ++nt) acc[mt][nt] = (f32x4){0.f, 0.f, 0.f, 0.f};

  int offA[2][4], offB[2][4];
  #pragma unroll
  for (int ks = 0; ks < 2; ++ks)
    #pragma unroll
    for (int mt = 0; mt < 4; ++mt) {
      offA[ks][mt] = (wr * 64 + mt * 16 + lr) * 64 + (((ks * 4 + lg)) ^ (lr & 7)) * 8;
      offB[ks][mt] = (wc * 64 + mt * 16 + lr) * 64 + (((ks * 4 + lg)) ^ (lr & 7)) * 8;
    }

  for (int k0 = 0; k0 < 16; ++k0) {
    #pragma unroll
    for (int i = 0; i < 4; ++i) {
      async_ld16(asrc[i], adst[i]);
      async_ld16(bsrc[i], bdst[i]);
      asrc[i] += 64;
      bsrc[i] += 64;
    }
    __syncthreads();  // vmcnt(0) drain -> tiles visible
    #pragma unroll
    for (int ks = 0; ks < 2; ++ks) {
      short8 af[4], bf[4];
      #pragma unroll
      for (int mt = 0; mt < 4; ++mt) af[mt] = *(const short8*)&As[offA[ks][mt]];
      #pragma unroll
      for (int nt = 0; nt < 4; ++nt) bf[nt] = *(const short8*)&Bs[offB[ks][nt]];
      #pragma unroll
      for (int mt = 0; mt < 4; ++mt)
        #pragma unroll
        for (int nt = 0; nt < 4; ++nt)
          acc[mt][nt] = __builtin_amdgcn_mfma_f32_16x16x32_bf16(
              af[mt], bf[nt], acc[mt][nt], 0, 0, 0);
    }
    __syncthreads();
  }

  const int mbase = m0 + wr * 64, nbase = n0 + wc * 64;
  if (mode == 0) {
    float* C = (float*)Cv;
    #pragma unroll
    for (int mt = 0; mt < 4; ++mt)
      #pragma unroll
      for (int nt = 0; nt < 4; ++nt) {
        const int n = nbase + nt * 16 + lr;
        const float bv = bias[n];
        #pragma unroll
        for (int i = 0; i < 4; ++i) {
          const int m = mbase + mt * 16 + lg * 4 + i;
          C[(size_t)m * 1024 + n] = acc[mt][nt][i] + bv;
        }
      }
  } else if (mode == 1) {
    unsigned short* C = (unsigned short*)Cv;
    #pragma unroll
    for (int mt = 0; mt < 4; ++mt)
      #pragma unroll
      for (int nt = 0; nt < 4; ++nt) {
        const int n = nbase + nt * 16 + lr, h = n >> 6, d = n & 63;
        const float bv = bias[n];
        #pragma unroll
        for (int i = 0; i < 4; ++i) {
          const int m = mbase + mt * 16 + lg * 4 + i;
          const int b = m >> 10, s = m & 1023;
          C[(size_t)(b * 16 + h) * 65536 + s * 64 + d] = f2bf(acc[mt][nt][i] + bv);
        }
      }
  } else {
    unsigned short* C = (unsigned short*)Cv;
    #pragma unroll
    for (int mt = 0; mt < 4; ++mt) {
      const int m4 = mbase + mt * 16 + lg * 4;
      const int b = m4 >> 10, s = m4 & 1023;
      #pragma unroll
      for (int nt = 0; nt < 4; ++nt) {
        const int n = nbase + nt * 16 + lr, h = n >> 6, d = n & 63;
        const float bv = bias[n];
        ushort4 o;
        o.x = f2bf(acc[mt][nt][0] + bv);
        o.y = f2bf(acc[mt][nt][1] + bv);
        o.z = f2bf(acc[mt][nt][2] + bv);
        o.w = f2bf(acc[mt][nt][3] + bv);
        *(ushort4*)&C[(size_t)(b * 16 + h) * 65536 + (size_t)d * 1024 + s] = o;
      }
    }
  }
}

// ---------------------------------------------------------------------------
// MFMA flash attention with gated rel-pos bias.
// Block: 256 thr (4 waves), 64 q-rows; wave w owns q rows [w*16, w*16+16).
// Per k-tile (64 keys): 8 MFMA scores + softmax (shfl over 16-lane groups,
// fragment layout col=lr, row=lg*4+i) + 8 MFMA PV.  K/Vt LDS source-swizzled;
// P bounced via padded LDS (stride 72 bf16 -> 2-way = free) into PV A-frags.
// ---------------------------------------------------------------------------
__global__ __launch_bounds__(256) void attn_mfma(
    const unsigned short* __restrict__ q_ws, const unsigned short* __restrict__ k_ws,
    const unsigned short* __restrict__ vt_ws, const float* __restrict__ gate_ws,
    const float* __restrict__ btab, unsigned short* __restrict__ ctx) {
  __shared__ __align__(16) unsigned short Qs[64 * 64];    // 8 KB
  __shared__ __align__(16) unsigned short Ks[64 * 64];    // 8 KB
  __shared__ __align__(16) unsigned short Vts[64 * 64];   // 8 KB
  __shared__ __align__(16) unsigned short Pls[4 * 16 * 72]; // 9 KB
  __shared__ float gates[64];

  const int t = threadIdx.x, w = t >> 6, l = t & 63;
  const int lr = l & 15, lg = l >> 4;
  const int bh = blockIdx.x, h = bh & 15, b = bh >> 4;
  const int q0 = blockIdx.y * 64;
  const size_t hb = (size_t)bh * 65536;
  const float* brow = btab + h * 2048 + 1023;

  #pragma unroll
  for (int i = 0; i < 2; ++i) {  // stage Q (swizzled src, linear dest)
    const int p = (w * 2 + i) * 64 + l, r = p >> 3, c = p & 7;
    const int cs = c ^ (r & 7);
    async_ld16(q_ws + hb + (size_t)(q0 + r) * 64 + cs * 8, &Qs[(w * 2 + i) * 512]);
  }
  if (t < 64) gates[t] = gate_ws[bh * 1024 + q0 + t];

  const unsigned short* ksrc[2];
  const unsigned short* vsrc[2];
  unsigned short* kdst[2];
  unsigned short* vdst[2];
  #pragma unroll
  for (int i = 0; i < 2; ++i) {
    const int p = (w * 2 + i) * 64 + l, r = p >> 3, c = p & 7;
    const int cs = c ^ (r & 7);
    ksrc[i] = k_ws + hb + (size_t)r * 64 + cs * 8;    // K rows = keys
    vsrc[i] = vt_ws + hb + (size_t)r * 1024 + cs * 8; // Vt rows = d
    kdst[i] = &Ks[(w * 2 + i) * 512];
    vdst[i] = &Vts[(w * 2 + i) * 512];
  }
  unsigned short* Pl = &Pls[w * 1152];

  float mcur[4] = {-1e30f, -1e30f, -1e30f, -1e30f};
  float lsum[4] = {0.f, 0.f, 0.f, 0.f};
  f32x4 acc_o[4];
  #pragma unroll
  for (int dt = 0; dt < 4; ++dt) acc_o[dt] = (f32x4){0.f, 0.f, 0.f, 0.f};

  const int qrow0 = q0 + w * 16 + lg * 4;
  int offQ[2], offP[2], offF[2][4];
  #pragma unroll
  for (int ks = 0; ks < 2; ++ks) {
    offQ[ks] = (w * 16 + lr) * 64 + ((ks * 4 + lg) ^ (lr & 7)) * 8;
    offP[ks] = lr * 72 + ks * 32 + lg * 8;
    #pragma unroll
    for (int nt = 0; nt < 4; ++nt)
      offF[ks][nt] = (nt * 16 + lr) * 64 + ((ks * 4 + lg) ^ (lr & 7)) * 8;
  }

  for (int kt = 0; kt < 16; ++kt) {
    __syncthreads();  // prev-iter frag reads done (and Q landed at kt=0)
    #pragma unroll
    for (int i = 0; i < 2; ++i) {
      async_ld16(ksrc[i], kdst[i]);
      async_ld16(vsrc[i], vdst[i]);
      ksrc[i] += 4096;
      vsrc[i] += 64;
    }
    __syncthreads();  // tiles visible

    // ---- QK^T: S[16 q][64 k] per wave, 8 mfma ---------------------------
    f32x4 accs[4];
    #pragma unroll
    for (int nt = 0; nt < 4; ++nt) accs[nt] = (f32x4){0.f, 0.f, 0.f, 0.f};
    #pragma unroll
    for (int ks = 0; ks < 2; ++ks) {
      const short8 aq = *(const short8*)&Qs[offQ[ks]];
      #pragma unroll
      for (int nt = 0; nt < 4; ++nt) {
        const short8 bk = *(const short8*)&Ks[offF[ks][nt]];
        accs[nt] = __builtin_amdgcn_mfma_f32_16x16x32_bf16(aq, bk, accs[nt], 0, 0, 0);
      }
    }

    // ---- online softmax over fragment rows ------------------------------
    #pragma unroll
    for (int i = 0; i < 4; ++i) {
      const int qrow = qrow0 + i;
      const float gt = gates[w * 16 + lg * 4 + i];
      float sv[4];
      #pragma unroll
      for (int nt = 0; nt < 4; ++nt) {
        const int kcol = kt * 64 + nt * 16 + lr;
        sv[nt] = 0.125f * accs[nt][i] + gt * brow[kcol - qrow];
      }
      float tm = fmaxf(fmaxf(sv[0], sv[1]), fmaxf(sv[2], sv[3]));
      #pragma unroll
      for (int msk = 1; msk <= 8; msk <<= 1) tm = fmaxf(tm, __shfl_xor(tm, msk));
      const float mn = fmaxf(mcur[i], tm);
      const float sc = __expf(mcur[i] - mn);
      mcur[i] = mn;
      float ps = 0.f;
      #pragma unroll
      for (int nt = 0; nt < 4; ++nt) {
        const float p = __expf(sv[nt] - mn);
        ps += p;
        Pl[(lg * 4 + i) * 72 + nt * 16 + lr] = f2bf(p);
      }
      #pragma unroll
      for (int msk = 1; msk <= 8; msk <<= 1) ps += __shfl_xor(ps, msk);
      lsum[i] = lsum[i] * sc + ps;
      #pragma unroll
      for (int dt = 0; dt < 4; ++dt) acc_o[dt][i] *= sc;
    }

    // ---- PV: O[16 q][64 d] += P @ V, 8 mfma ------------------------------
    #pragma unroll
    for (int ks = 0; ks < 2; ++ks) {
      const short8 ap = *(const short8*)&Pl[offP[ks]];
      #pragma unroll
      for (int dt = 0; dt < 4; ++dt) {
        const short8 bv = *(const short8*)&Vts[offF[ks][dt]];
        acc_o[dt] = __builtin_amdgcn_mfma_f32_16x16x32_bf16(ap, bv, acc_o[dt], 0, 0, 0);
      }
    }
  }

  // ---- epilogue: ctx[(b*1024+s)*1024 + h*64 + d] bf16 ---------------------
  #pragma unroll
  for (int i = 0; i < 4; ++i) {
    const float inv = 1.f / lsum[i];
    const size_t rowoff = ((size_t)(b * 1024 + qrow0 + i) * 16 + h) * 64;
    #pragma unroll
    for (int dt = 0; dt < 4; ++dt)
      ctx[rowoff + dt * 16 + lr] = f2bf(acc_o[dt][i] * inv);
  }
}

// ---------------------------------------------------------------------------
extern "C" void kernel_launch(void* const* d_in, const int* in_sizes, int n_in,
                              void* d_out, int out_size, void* d_ws, size_t ws_size,
                              hipStream_t stream) {
  const float* x    = (const float*)d_in[0];
  const float* Wq   = (const float*)d_in[1];
  const float* bq   = (const float*)d_in[2];
  const float* Wk   = (const float*)d_in[3];
  const float* bk   = (const float*)d_in[4];
  const float* Wv   = (const float*)d_in[5];
  const float* bv   = (const float*)d_in[6];
  const float* Wo   = (const float*)d_in[7];
  const float* bo   = (const float*)d_in[8];
  const float* rel  = (const float*)d_in[9];
  const float* gw   = (const float*)d_in[10];
  const float* gb   = (const float*)d_in[11];
  const float* gcst = (const float*)d_in[12];
  float* out = (float*)d_out;

  char* ws = (char*)d_ws;
  unsigned short* x_bf  = (unsigned short*)(ws);
  unsigned short* wtq   = (unsigned short*)(ws + 16777216);
  unsigned short* wtk   = (unsigned short*)(ws + 18874368);
  unsigned short* wtv   = (unsigned short*)(ws + 20971520);
  unsigned short* wto   = (unsigned short*)(ws + 23068672);
  unsigned short* q_ws  = (unsigned short*)(ws + 25165824);
  unsigned short* k_ws  = (unsigned short*)(ws + 41943040);
  unsigned short* vt_ws = (unsigned short*)(ws + 58720256);
  unsigned short* ctx   = (unsigned short*)(ws + 75497472);
  float* gate = (float*)(ws + 92274688);
  float* btab = (float*)(ws + 92798976);

  cvt_x      <<<dim3(8192),   256, 0, stream>>>(x, x_bf);
  transW     <<<dim3(16, 16), 256, 0, stream>>>(Wq, wtq);
  transW     <<<dim3(16, 16), 256, 0, stream>>>(Wk, wtk);
  transW     <<<dim3(16, 16), 256, 0, stream>>>(Wv, wtv);
  transW     <<<dim3(16, 16), 256, 0, stream>>>(Wo, wto);
  prep_btab  <<<dim3(8),      256, 0, stream>>>(rel, btab);
  gate_kernel<<<dim3(8192),   256, 0, stream>>>(x, gw, gb, gcst, gate);
  gemm_bf    <<<dim3(64, 8),  256, 0, stream>>>(x_bf, wtq, bq, q_ws, 1);
  gemm_bf    <<<dim3(64, 8),  256, 0, stream>>>(x_bf, wtk, bk, k_ws, 1);
  gemm_bf    <<<dim3(64, 8),  256, 0, stream>>>(x_bf, wtv, bv, vt_ws, 2);
  attn_mfma  <<<dim3(128, 16),256, 0, stream>>>(q_ws, k_ws, vt_ws, gate, btab, ctx);
  gemm_bf    <<<dim3(64, 8),  256, 0, stream>>>(ctx, wto, bo, out, 0);
}

// Round 3
// 298.703 us; speedup vs baseline: 7.1258x; 1.2908x over previous
//
#include <hip/hip_runtime.h>
#include <hip/hip_bf16.h>
#include <math.h>

// ---------------------------------------------------------------------------
// WavLM self-attention, bf16-MFMA v2.
//   B=8 S=1024 H=16 D=64 E=1024, SCALING=0.125 (folded into q_ws)
// Round-3 changes vs validated round-2:
//   * swapped QK^T (S^T layout) -> per-lane row softmax, 2 shfls not 32
//   * bias table staged to LDS per block (no per-element global loads)
//   * single-barrier K/V double-buffer prefetch pipeline in attn
//   * QKV fused into one GEMM launch; cvt_x fused into gate; transW fused
//   * defer-max rescale skip (THR=8, exact)
// Workspace (bytes):
//   x_bf   [8M bf16]            @ 0
//   wt_all [4x1M bf16, W^T]     @ 16777216   (q,k,v,o)
//   q_ws   [8M bf16, (bh,s,d)]  @ 25165824   (pre-scaled by 0.125)
//   k_ws   [8M bf16, (bh,s,d)]  @ 41943040
//   vt_ws  [8M bf16, (bh,d,s)]  @ 58720256
//   ctx    [8M bf16, (b,s,e)]   @ 75497472
//   gate   [128K f32]           @ 92274688
//   btab   [32K f32]            @ 92798976
// ---------------------------------------------------------------------------

typedef __attribute__((ext_vector_type(8))) short short8;
typedef __attribute__((ext_vector_type(4))) float f32x4;

#define LDSP(p) ((__attribute__((address_space(3))) void*)(p))
#define GLBP(p) ((const __attribute__((address_space(1))) void*)(p))

__device__ __forceinline__ void async_ld16(const void* src, void* dst) {
  __builtin_amdgcn_global_load_lds(GLBP(src), LDSP(dst), 16, 0, 0);
}
__device__ __forceinline__ unsigned short f2bf(float f) {
  __hip_bfloat16 h = __float2bfloat16(f);
  return __builtin_bit_cast(unsigned short, h);
}

// ---------------------------------------------------------------------------
// rel-pos bias table, double math = numpy-exact bucketing.
// ---------------------------------------------------------------------------
__global__ void prep_btab(const float* __restrict__ rel_embed,
                          float* __restrict__ btab) {
  const int idx = blockIdx.x * 256 + threadIdx.x;
  if (idx >= 2047) return;
  const int rel = idx - 1023;
  int bucket = (rel > 0) ? 16 : 0;
  const int rp = rel < 0 ? -rel : rel;
  if (rp < 8) {
    bucket += rp;
  } else {
    const double lv = log((double)rp / 8.0) / log(16.0) * 8.0;
    int large = 8 + (int)lv;
    bucket += (large < 15) ? large : 15;
  }
  #pragma unroll
  for (int h = 0; h < 16; ++h)
    btab[h * 2048 + idx] = rel_embed[bucket * 16 + h];
}

// ---------------------------------------------------------------------------
// fused x fp32->bf16 + gate computation. One block per (b,s).
// ---------------------------------------------------------------------------
__global__ __launch_bounds__(256) void cvt_gate(
    const float* __restrict__ x, const float* __restrict__ gw,
    const float* __restrict__ gb, const float* __restrict__ gcst,
    unsigned short* __restrict__ xb, float* __restrict__ gate_ws) {
  __shared__ __align__(16) float xr[1024];
  const int bs = blockIdx.x, t = threadIdx.x;
  const float4 v = *(const float4*)&x[(size_t)bs * 1024 + t * 4];
  *(float4*)&xr[t * 4] = v;
  ushort4 o;
  o.x = f2bf(v.x); o.y = f2bf(v.y); o.z = f2bf(v.z); o.w = f2bf(v.w);
  *(ushort4*)&xb[(size_t)bs * 1024 + t * 4] = o;
  __syncthreads();
  const int h = t >> 4, i = t & 15;
  float pa = 0.f, pb = 0.f;
  #pragma unroll
  for (int j = 0; j < 4; ++j) {
    const int d = i * 4 + j;
    const float xv = xr[h * 64 + d];
    const float* wr = &gw[d * 8];
    pa += xv * (wr[0] + wr[1] + wr[2] + wr[3]);
    pb += xv * (wr[4] + wr[5] + wr[6] + wr[7]);
  }
  #pragma unroll
  for (int msk = 1; msk <= 8; msk <<= 1) {
    pa += __shfl_xor(pa, msk);
    pb += __shfl_xor(pb, msk);
  }
  if (i == 0) {
    const float ba = gb[0] + gb[1] + gb[2] + gb[3];
    const float bb = gb[4] + gb[5] + gb[6] + gb[7];
    const float ga  = 1.f / (1.f + __expf(-(pa + ba)));
    const float gbv = 1.f / (1.f + __expf(-(pb + bb)));
    const float gv  = ga * (gbv * gcst[h] - 1.f) + 2.f;
    const int b = bs >> 10, s = bs & 1023;
    gate_ws[(b * 16 + h) * 1024 + s] = gv;
  }
}

// ---------------------------------------------------------------------------
// 4x W[k][n] fp32 -> Wt[n][k] bf16, fused (blockIdx.z selects weight).
// ---------------------------------------------------------------------------
__global__ __launch_bounds__(256) void transW4(
    const float* __restrict__ W0, const float* __restrict__ W1,
    const float* __restrict__ W2, const float* __restrict__ W3,
    unsigned short* __restrict__ Wt_all) {
  __shared__ __align__(16) float tile[64][68];
  const int z = blockIdx.z;
  const float* W = (z == 0) ? W0 : (z == 1) ? W1 : (z == 2) ? W2 : W3;
  unsigned short* Wt = Wt_all + (size_t)z * 1048576;
  const int n0 = blockIdx.x * 64, k0 = blockIdx.y * 64;
  const int c = (threadIdx.x & 15) * 4, r = threadIdx.x >> 4;
  #pragma unroll
  for (int i = 0; i < 4; ++i)
    *(float4*)&tile[r + i * 16][c] =
        *(const float4*)&W[(size_t)(k0 + r + i * 16) * 1024 + n0 + c];
  __syncthreads();
  #pragma unroll
  for (int i = 0; i < 4; ++i) {
    const int n = r + i * 16;
    ushort4 o;
    o.x = f2bf(tile[c + 0][n]); o.y = f2bf(tile[c + 1][n]);
    o.z = f2bf(tile[c + 2][n]); o.w = f2bf(tile[c + 3][n]);
    *(ushort4*)&Wt[(size_t)(n0 + n) * 1024 + k0 + c] = o;
  }
}

// ---------------------------------------------------------------------------
// Shared GEMM core: acc[4][4] += A_tile(128x1024) @ Bt_tile(128x1024)^T.
// Same structure as validated round-2 kernel (src-swizzled global_load_lds).
// ---------------------------------------------------------------------------
__device__ __forceinline__ void gemm_core(
    const unsigned short* __restrict__ A, const unsigned short* __restrict__ Bt,
    unsigned short* As, unsigned short* Bs, const int m0, const int n0,
    f32x4 acc[4][4]) {
  const int t = threadIdx.x, w = t >> 6, l = t & 63;
  const int lr = l & 15, lg = l >> 4;
  const int wr = w >> 1, wc = w & 1;

  const unsigned short* asrc[4];
  const unsigned short* bsrc[4];
  unsigned short* adst[4];
  unsigned short* bdst[4];
  #pragma unroll
  for (int i = 0; i < 4; ++i) {
    const int p = (w * 4 + i) * 64 + l, r = p >> 3, c = p & 7;
    const int cs = c ^ (r & 7);
    asrc[i] = A + (size_t)(m0 + r) * 1024 + cs * 8;
    bsrc[i] = Bt + (size_t)(n0 + r) * 1024 + cs * 8;
    adst[i] = &As[(w * 4 + i) * 512];
    bdst[i] = &Bs[(w * 4 + i) * 512];
  }

  int offA[2][4], offB[2][4];
  #pragma unroll
  for (int ks = 0; ks < 2; ++ks)
    #pragma unroll
    for (int mt = 0; mt < 4; ++mt) {
      offA[ks][mt] = (wr * 64 + mt * 16 + lr) * 64 + ((ks * 4 + lg) ^ (lr & 7)) * 8;
      offB[ks][mt] = (wc * 64 + mt * 16 + lr) * 64 + ((ks * 4 + lg) ^ (lr & 7)) * 8;
    }

  for (int k0 = 0; k0 < 16; ++k0) {
    #pragma unroll
    for (int i = 0; i < 4; ++i) {
      async_ld16(asrc[i], adst[i]);
      async_ld16(bsrc[i], bdst[i]);
      asrc[i] += 64;
      bsrc[i] += 64;
    }
    __syncthreads();
    #pragma unroll
    for (int ks = 0; ks < 2; ++ks) {
      short8 af[4], bf[4];
      #pragma unroll
      for (int mt = 0; mt < 4; ++mt) af[mt] = *(const short8*)&As[offA[ks][mt]];
      #pragma unroll
      for (int nt = 0; nt < 4; ++nt) bf[nt] = *(const short8*)&Bs[offB[ks][nt]];
      #pragma unroll
      for (int mt = 0; mt < 4; ++mt)
        #pragma unroll
        for (int nt = 0; nt < 4; ++nt)
          acc[mt][nt] = __builtin_amdgcn_mfma_f32_16x16x32_bf16(
              af[mt], bf[nt], acc[mt][nt], 0, 0, 0);
    }
    __syncthreads();
  }
}

// ---------------------------------------------------------------------------
// Fused QKV GEMM: blockIdx.y in [0,24): which = y>>3 (0=q 1=k 2=v).
// q scaled by 0.125; q/k scatter (bh,s,d); v scatter transposed (bh,d,s).
// ---------------------------------------------------------------------------
__global__ __launch_bounds__(256) void gemm_qkv(
    const unsigned short* __restrict__ A, const unsigned short* __restrict__ wt_all,
    const float* __restrict__ bq, const float* __restrict__ bk,
    const float* __restrict__ bv, unsigned short* __restrict__ q_ws,
    unsigned short* __restrict__ k_ws, unsigned short* __restrict__ vt_ws) {
  __shared__ __align__(16) unsigned short As[128 * 64];
  __shared__ __align__(16) unsigned short Bs[128 * 64];
  const int which = blockIdx.y >> 3;
  const int m0 = blockIdx.x * 128, n0 = (blockIdx.y & 7) * 128;
  const unsigned short* Bt = wt_all + (size_t)which * 1048576;
  const float* bias = (which == 0) ? bq : (which == 1) ? bk : bv;

  f32x4 acc[4][4];
  #pragma unroll
  for (int mt = 0; mt < 4; ++mt)
    #pragma unroll
    for (int nt = 0; nt < 4; ++nt) acc[mt][nt] = (f32x4){0.f, 0.f, 0.f, 0.f};
  gemm_core(A, Bt, As, Bs, m0, n0, acc);

  const int t = threadIdx.x, w = t >> 6, l = t & 63;
  const int lr = l & 15, lg = l >> 4;
  const int wr = w >> 1, wc = w & 1;
  const int mbase = m0 + wr * 64, nbase = n0 + wc * 64;

  if (which == 2) {
    #pragma unroll
    for (int mt = 0; mt < 4; ++mt) {
      const int m4 = mbase + mt * 16 + lg * 4;
      const int b = m4 >> 10, s = m4 & 1023;
      #pragma unroll
      for (int nt = 0; nt < 4; ++nt) {
        const int n = nbase + nt * 16 + lr, h = n >> 6, d = n & 63;
        const float bvv = bias[n];
        ushort4 o;
        o.x = f2bf(acc[mt][nt][0] + bvv);
        o.y = f2bf(acc[mt][nt][1] + bvv);
        o.z = f2bf(acc[mt][nt][2] + bvv);
        o.w = f2bf(acc[mt][nt][3] + bvv);
        *(ushort4*)&vt_ws[(size_t)(b * 16 + h) * 65536 + (size_t)d * 1024 + s] = o;
      }
    }
  } else {
    unsigned short* dst = (which == 0) ? q_ws : k_ws;
    const float scale = (which == 0) ? 0.125f : 1.0f;
    #pragma unroll
    for (int mt = 0; mt < 4; ++mt)
      #pragma unroll
      for (int nt = 0; nt < 4; ++nt) {
        const int n = nbase + nt * 16 + lr, h = n >> 6, d = n & 63;
        const float bvv = bias[n];
        #pragma unroll
        for (int i = 0; i < 4; ++i) {
          const int m = mbase + mt * 16 + lg * 4 + i;
          const int b = m >> 10, s = m & 1023;
          dst[(size_t)(b * 16 + h) * 65536 + s * 64 + d] =
              f2bf((acc[mt][nt][i] + bvv) * scale);
        }
      }
  }
}

// ---------------------------------------------------------------------------
// Output projection GEMM (fp32 out).
// ---------------------------------------------------------------------------
__global__ __launch_bounds__(256) void gemm_out(
    const unsigned short* __restrict__ A, const unsigned short* __restrict__ Bt,
    const float* __restrict__ bias, float* __restrict__ C) {
  __shared__ __align__(16) unsigned short As[128 * 64];
  __shared__ __align__(16) unsigned short Bs[128 * 64];
  const int m0 = blockIdx.x * 128, n0 = blockIdx.y * 128;
  f32x4 acc[4][4];
  #pragma unroll
  for (int mt = 0; mt < 4; ++mt)
    #pragma unroll
    for (int nt = 0; nt < 4; ++nt) acc[mt][nt] = (f32x4){0.f, 0.f, 0.f, 0.f};
  gemm_core(A, Bt, As, Bs, m0, n0, acc);

  const int t = threadIdx.x, w = t >> 6, l = t & 63;
  const int lr = l & 15, lg = l >> 4;
  const int wr = w >> 1, wc = w & 1;
  const int mbase = m0 + wr * 64, nbase = n0 + wc * 64;
  #pragma unroll
  for (int mt = 0; mt < 4; ++mt)
    #pragma unroll
    for (int nt = 0; nt < 4; ++nt) {
      const int n = nbase + nt * 16 + lr;
      const float bvv = bias[n];
      #pragma unroll
      for (int i = 0; i < 4; ++i) {
        const int m = mbase + mt * 16 + lg * 4 + i;
        C[(size_t)m * 1024 + n] = acc[mt][nt][i] + bvv;
      }
    }
}

// ---------------------------------------------------------------------------
// MFMA flash attention v2: swapped QK^T, per-lane softmax, 1 barrier/tile,
// K/V double-buffer prefetch, LDS bias table, defer-max.
// Block 256 thr (4 waves), 64 q rows (16/wave); K/V tiles of 64.
// ---------------------------------------------------------------------------
__global__ __launch_bounds__(256) void attn_mfma(
    const unsigned short* __restrict__ q_ws, const unsigned short* __restrict__ k_ws,
    const unsigned short* __restrict__ vt_ws, const float* __restrict__ gate_ws,
    const float* __restrict__ btab, unsigned short* __restrict__ ctx) {
  __shared__ __align__(16) unsigned short Ks[2][64 * 64];   // 16 KB
  __shared__ __align__(16) unsigned short Vts[2][64 * 64];  // 16 KB
  __shared__ __align__(16) unsigned short QPs[64 * 64];     // 8 KB: Q then P
  __shared__ __align__(16) float biasl[1088];               // 4.25 KB
  __shared__ float gates[64];
  __shared__ float scl[64];

  const int t = threadIdx.x, w = t >> 6, l = t & 63;
  const int lr = l & 15, lg = l >> 4;
  const int bh = blockIdx.x, h = bh & 15, b = bh >> 4;
  const int q0 = blockIdx.y * 64;
  const size_t hb = (size_t)bh * 65536;

  // --- stage Q (wave-own 16 rows, swizzled source) ------------------------
  #pragma unroll
  for (int i = 0; i < 2; ++i) {
    const int p = (w * 2 + i) * 64 + l, r = p >> 3, c = p & 7;
    const int cs = c ^ (r & 7);
    async_ld16(q_ws + hb + (size_t)(q0 + r) * 64 + cs * 8, &QPs[(w * 2 + i) * 512]);
  }
  // --- stage K/V tile 0 ----------------------------------------------------
  #pragma unroll
  for (int i = 0; i < 2; ++i) {
    const int p = (w * 2 + i) * 64 + l, r = p >> 3, c = p & 7;
    const int cs = c ^ (r & 7);
    async_ld16(k_ws + hb + (size_t)r * 64 + cs * 8, &Ks[0][(w * 2 + i) * 512]);
    async_ld16(vt_ws + hb + (size_t)r * 1024 + cs * 8, &Vts[0][(w * 2 + i) * 512]);
  }
  // --- stage bias slice: btab[h][960-q0 .. +1088) --------------------------
  {
    const float* bt = btab + h * 2048 + (960 - q0);
    for (int u = t * 4; u < 1088; u += 1024)
      *(float4*)&biasl[u] = *(const float4*)&bt[u];
  }
  if (t < 64) gates[t] = gate_ws[bh * 1024 + q0 + t];
  __syncthreads();  // S(0): Q, K0, V0 landed; bias/gates visible

  // --- hoist Q fragments (reads own region before P overwrites it) --------
  short8 qf[2];
  #pragma unroll
  for (int ks = 0; ks < 2; ++ks)
    qf[ks] = *(const short8*)&QPs[(w * 16 + lr) * 64 + ((ks * 4 + lg) ^ (lr & 7)) * 8];

  // --- P tile offsets (bytes, XOR-swizzled, wave region = w*2048 B) --------
  int pwoff[4], proff[2], offF[2][4];
  #pragma unroll
  for (int nt = 0; nt < 4; ++nt)
    pwoff[nt] = w * 2048 + ((lr * 128 + nt * 32 + lg * 8) ^ ((lr & 7) << 4));
  #pragma unroll
  for (int ks = 0; ks < 2; ++ks) {
    proff[ks] = w * 2048 + ((lr * 128 + ks * 64 + lg * 16) ^ ((lr & 7) << 4));
    #pragma unroll
    for (int nt = 0; nt < 4; ++nt)
      offF[ks][nt] = (nt * 16 + lr) * 64 + ((ks * 4 + lg) ^ (lr & 7)) * 8;
  }

  float mcur = -1e30f, lsum = 0.f;
  f32x4 acc_o[4];
  #pragma unroll
  for (int dt = 0; dt < 4; ++dt) acc_o[dt] = (f32x4){0.f, 0.f, 0.f, 0.f};
  const float gt = gates[w * 16 + lr];
  const int ub = 63 - w * 16 - lr;  // bias idx base
  char* QPb = (char*)QPs;

  int cur = 0;
  for (int kt = 0; kt < 16; ++kt) {
    if (kt) {
      asm volatile("s_waitcnt vmcnt(0) lgkmcnt(0)" ::: "memory");
      __builtin_amdgcn_s_barrier();
      __builtin_amdgcn_sched_barrier(0);
    }
    // prefetch next K/V tile (safe: buf cur^1 last read 1 barrier ago)
    if (kt + 1 < 16) {
      #pragma unroll
      for (int i = 0; i < 2; ++i) {
        const int p = (w * 2 + i) * 64 + l, r = p >> 3, c = p & 7;
        const int cs = c ^ (r & 7);
        async_ld16(k_ws + hb + (size_t)(kt + 1) * 4096 + (size_t)r * 64 + cs * 8,
                   &Ks[cur ^ 1][(w * 2 + i) * 512]);
        async_ld16(vt_ws + hb + (size_t)r * 1024 + (kt + 1) * 64 + cs * 8,
                   &Vts[cur ^ 1][(w * 2 + i) * 512]);
      }
    }

    // ---- QK^T swapped: accs[nt][i] = S^T[k = nt*16+lg*4+i][q = lr] -------
    f32x4 accs[4];
    #pragma unroll
    for (int nt = 0; nt < 4; ++nt) accs[nt] = (f32x4){0.f, 0.f, 0.f, 0.f};
    #pragma unroll
    for (int ks = 0; ks < 2; ++ks) {
      #pragma unroll
      for (int nt = 0; nt < 4; ++nt) {
        const short8 kf = *(const short8*)&Ks[cur][offF[ks][nt]];
        accs[nt] = __builtin_amdgcn_mfma_f32_16x16x32_bf16(kf, qf[ks], accs[nt], 0, 0, 0);
      }
    }

    // ---- bias + per-lane row max ----------------------------------------
    const int bb = kt * 64 + ub + lg * 4;
    float tm = -1e30f;
    #pragma unroll
    for (int nt = 0; nt < 4; ++nt) {
      #pragma unroll
      for (int i = 0; i < 4; ++i) {
        const float sv = accs[nt][i] + gt * biasl[bb + nt * 16 + i];
        accs[nt][i] = sv;
        tm = fmaxf(tm, sv);
      }
    }
    tm = fmaxf(tm, __shfl_xor(tm, 16));
    tm = fmaxf(tm, __shfl_xor(tm, 32));

    const int skip = __all(tm <= mcur + 8.0f);  // defer-max (exact)
    float sc = 1.0f;
    if (!skip) {
      const float mn = fmaxf(mcur, tm);
      sc = __expf(mcur - mn);
      mcur = mn;
      if (lg == 0) scl[w * 16 + lr] = sc;
    }

    // ---- p = exp(sv - mcur), pack to bf16, write P, row sum --------------
    float ps = 0.f;
    #pragma unroll
    for (int nt = 0; nt < 4; ++nt) {
      float p0 = __expf(accs[nt][0] - mcur);
      float p1 = __expf(accs[nt][1] - mcur);
      float p2 = __expf(accs[nt][2] - mcur);
      float p3 = __expf(accs[nt][3] - mcur);
      ps += (p0 + p1) + (p2 + p3);
      short4 pk;
      pk.x = (short)f2bf(p0); pk.y = (short)f2bf(p1);
      pk.z = (short)f2bf(p2); pk.w = (short)f2bf(p3);
      *(short4*)(QPb + pwoff[nt]) = pk;
    }
    ps += __shfl_xor(ps, 16);
    ps += __shfl_xor(ps, 32);
    lsum = skip ? (lsum + ps) : (lsum * sc + ps);

    // fence: P/scl writes visible to this wave's reads (wave-private data)
    asm volatile("s_waitcnt lgkmcnt(0)" ::: "memory");
    __builtin_amdgcn_sched_barrier(0);

    // ---- rescale acc_o (only when max moved) -----------------------------
    if (!skip) {
      float s0 = scl[w * 16 + lg * 4 + 0];
      float s1 = scl[w * 16 + lg * 4 + 1];
      float s2 = scl[w * 16 + lg * 4 + 2];
      float s3 = scl[w * 16 + lg * 4 + 3];
      #pragma unroll
      for (int dt = 0; dt < 4; ++dt) {
        acc_o[dt][0] *= s0; acc_o[dt][1] *= s1;
        acc_o[dt][2] *= s2; acc_o[dt][3] *= s3;
      }
    }

    // ---- PV: O[q][d] += P[q][k] V[k][d] ---------------------------------
    #pragma unroll
    for (int ks = 0; ks < 2; ++ks) {
      const short8 pf = *(const short8*)(QPb + proff[ks]);
      #pragma unroll
      for (int dt = 0; dt < 4; ++dt) {
        const short8 vf = *(const short8*)&Vts[cur][offF[ks][dt]];
        acc_o[dt] = __builtin_amdgcn_mfma_f32_16x16x32_bf16(pf, vf, acc_o[dt], 0, 0, 0);
      }
    }
    cur ^= 1;
  }

  // ---- epilogue -----------------------------------------------------------
  if (lg == 0) scl[w * 16 + lr] = 1.0f / lsum;
  asm volatile("s_waitcnt lgkmcnt(0)" ::: "memory");
  __builtin_amdgcn_sched_barrier(0);
  float inv[4];
  #pragma unroll
  for (int i = 0; i < 4; ++i) inv[i] = scl[w * 16 + lg * 4 + i];
  #pragma unroll
  for (int i = 0; i < 4; ++i) {
    const int q = q0 + w * 16 + lg * 4 + i;
    const size_t rowoff = ((size_t)(b * 1024 + q) * 16 + h) * 64;
    #pragma unroll
    for (int dt = 0; dt < 4; ++dt)
      ctx[rowoff + dt * 16 + lr] = f2bf(acc_o[dt][i] * inv[i]);
  }
}

// ---------------------------------------------------------------------------
extern "C" void kernel_launch(void* const* d_in, const int* in_sizes, int n_in,
                              void* d_out, int out_size, void* d_ws, size_t ws_size,
                              hipStream_t stream) {
  const float* x    = (const float*)d_in[0];
  const float* Wq   = (const float*)d_in[1];
  const float* bq   = (const float*)d_in[2];
  const float* Wk   = (const float*)d_in[3];
  const float* bk   = (const float*)d_in[4];
  const float* Wv   = (const float*)d_in[5];
  const float* bv   = (const float*)d_in[6];
  const float* Wo   = (const float*)d_in[7];
  const float* bo   = (const float*)d_in[8];
  const float* rel  = (const float*)d_in[9];
  const float* gw   = (const float*)d_in[10];
  const float* gb   = (const float*)d_in[11];
  const float* gcst = (const float*)d_in[12];
  float* out = (float*)d_out;

  char* ws = (char*)d_ws;
  unsigned short* x_bf   = (unsigned short*)(ws);
  unsigned short* wt_all = (unsigned short*)(ws + 16777216);
  unsigned short* q_ws   = (unsigned short*)(ws + 25165824);
  unsigned short* k_ws   = (unsigned short*)(ws + 41943040);
  unsigned short* vt_ws  = (unsigned short*)(ws + 58720256);
  unsigned short* ctx    = (unsigned short*)(ws + 75497472);
  float* gate = (float*)(ws + 92274688);
  float* btab = (float*)(ws + 92798976);

  cvt_gate <<<dim3(8192),       256, 0, stream>>>(x, gw, gb, gcst, x_bf, gate);
  transW4  <<<dim3(16, 16, 4),  256, 0, stream>>>(Wq, Wk, Wv, Wo, wt_all);
  prep_btab<<<dim3(8),          256, 0, stream>>>(rel, btab);
  gemm_qkv <<<dim3(64, 24),     256, 0, stream>>>(x_bf, wt_all, bq, bk, bv,
                                                  q_ws, k_ws, vt_ws);
  attn_mfma<<<dim3(128, 16),    256, 0, stream>>>(q_ws, k_ws, vt_ws, gate, btab, ctx);
  gemm_out <<<dim3(64, 8),      256, 0, stream>>>(ctx, wt_all + 3 * 1048576, bo, out);
}

// Round 4
// 292.036 us; speedup vs baseline: 7.2885x; 1.0228x over previous
//
#include <hip/hip_runtime.h>
#include <hip/hip_bf16.h>
#include <math.h>

// ---------------------------------------------------------------------------
// WavLM self-attention, bf16-MFMA v3.
//   B=8 S=1024 H=16 D=64 E=1024; q pre-scaled by 0.125*log2(e) (exp2 softmax)
// Round-4 changes vs validated round-3:
//   * attn: Q direct global->reg, V single-buffered w/ counted vmcnt(2),
//     LDS 46->36.8KB (3->4 blocks/CU), exp2 softmax, setprio on MFMA
//   * GEMM q/k/out epilogues: operand-swapped MFMA (C^T) -> wide stores
//   * prep kernels fused into one launch
// Workspace (bytes): same layout as round-3.
// ---------------------------------------------------------------------------

typedef __attribute__((ext_vector_type(8))) short short8;
typedef __attribute__((ext_vector_type(4))) float f32x4;

#define LDSP(p) ((__attribute__((address_space(3))) void*)(p))
#define GLBP(p) ((const __attribute__((address_space(1))) void*)(p))

__device__ __forceinline__ void async_ld16(const void* src, void* dst) {
  __builtin_amdgcn_global_load_lds(GLBP(src), LDSP(dst), 16, 0, 0);
}
__device__ __forceinline__ unsigned short f2bf(float f) {
  __hip_bfloat16 h = __float2bfloat16(f);
  return __builtin_bit_cast(unsigned short, h);
}
#if __has_builtin(__builtin_amdgcn_exp2f)
#define EXP2(x) __builtin_amdgcn_exp2f(x)
#else
#define EXP2(x) exp2f(x)
#endif

// ---------------------------------------------------------------------------
// Fused prep: [0,8192) cvt+gate, [8192,9216) transW x4, [9216,9224) btab.
// ---------------------------------------------------------------------------
__global__ __launch_bounds__(256) void prep_all(
    const float* __restrict__ x, const float* __restrict__ gw,
    const float* __restrict__ gb, const float* __restrict__ gcst,
    const float* __restrict__ W0, const float* __restrict__ W1,
    const float* __restrict__ W2, const float* __restrict__ W3,
    const float* __restrict__ rel_embed,
    unsigned short* __restrict__ xb, float* __restrict__ gate_ws,
    unsigned short* __restrict__ Wt_all, float* __restrict__ btab) {
  __shared__ __align__(16) float tile[64][68];
  const int bid = blockIdx.x, t = threadIdx.x;
  if (bid < 8192) {
    // ---- x -> bf16 + gate ------------------------------------------------
    float* xr = &tile[0][0];
    const float4 v = *(const float4*)&x[(size_t)bid * 1024 + t * 4];
    *(float4*)&xr[t * 4] = v;
    ushort4 o;
    o.x = f2bf(v.x); o.y = f2bf(v.y); o.z = f2bf(v.z); o.w = f2bf(v.w);
    *(ushort4*)&xb[(size_t)bid * 1024 + t * 4] = o;
    __syncthreads();
    const int h = t >> 4, i = t & 15;
    float pa = 0.f, pb = 0.f;
    #pragma unroll
    for (int j = 0; j < 4; ++j) {
      const int d = i * 4 + j;
      const float xv = xr[h * 64 + d];
      const float* wr = &gw[d * 8];
      pa += xv * (wr[0] + wr[1] + wr[2] + wr[3]);
      pb += xv * (wr[4] + wr[5] + wr[6] + wr[7]);
    }
    #pragma unroll
    for (int msk = 1; msk <= 8; msk <<= 1) {
      pa += __shfl_xor(pa, msk);
      pb += __shfl_xor(pb, msk);
    }
    if (i == 0) {
      const float ba = gb[0] + gb[1] + gb[2] + gb[3];
      const float bb = gb[4] + gb[5] + gb[6] + gb[7];
      const float ga  = 1.f / (1.f + __expf(-(pa + ba)));
      const float gbv = 1.f / (1.f + __expf(-(pb + bb)));
      const float gv  = ga * (gbv * gcst[h] - 1.f) + 2.f;
      const int b = bid >> 10, s = bid & 1023;
      gate_ws[(b * 16 + h) * 1024 + s] = gv;
    }
  } else if (bid < 9216) {
    // ---- W[k][n] -> Wt[n][k] bf16 ---------------------------------------
    const int zz = bid - 8192;
    const int z = zz >> 8;
    const float* W = (z == 0) ? W0 : (z == 1) ? W1 : (z == 2) ? W2 : W3;
    unsigned short* Wt = Wt_all + (size_t)z * 1048576;
    const int n0 = (zz & 15) * 64, k0 = ((zz >> 4) & 15) * 64;
    const int c = (t & 15) * 4, r = t >> 4;
    #pragma unroll
    for (int i = 0; i < 4; ++i)
      *(float4*)&tile[r + i * 16][c] =
          *(const float4*)&W[(size_t)(k0 + r + i * 16) * 1024 + n0 + c];
    __syncthreads();
    #pragma unroll
    for (int i = 0; i < 4; ++i) {
      const int n = r + i * 16;
      ushort4 o;
      o.x = f2bf(tile[c + 0][n]); o.y = f2bf(tile[c + 1][n]);
      o.z = f2bf(tile[c + 2][n]); o.w = f2bf(tile[c + 3][n]);
      *(ushort4*)&Wt[(size_t)(n0 + n) * 1024 + k0 + c] = o;
    }
  } else {
    // ---- bias table (double math = numpy-exact) --------------------------
    const int idx = (bid - 9216) * 256 + t;
    if (idx < 2047) {
      const int rel = idx - 1023;
      int bucket = (rel > 0) ? 16 : 0;
      const int rp = rel < 0 ? -rel : rel;
      if (rp < 8) {
        bucket += rp;
      } else {
        const double lv = log((double)rp / 8.0) / log(16.0) * 8.0;
        int large = 8 + (int)lv;
        bucket += (large < 15) ? large : 15;
      }
      #pragma unroll
      for (int h = 0; h < 16; ++h)
        btab[h * 2048 + idx] = rel_embed[bucket * 16 + h];
    }
  }
}

// ---------------------------------------------------------------------------
// Shared GEMM core (validated 2-barrier structure).
// SWAP=1: mfma(b,a) -> acc[mt][nt][ii] = C[m=mbase+mt*16+lr][n=nbase+nt*16+lg*4+ii]
// SWAP=0: mfma(a,b) -> acc[mt][nt][ii] = C[m=mbase+mt*16+lg*4+ii][n=nbase+nt*16+lr]
// ---------------------------------------------------------------------------
template <int SWAP>
__device__ __forceinline__ void gemm_core(
    const unsigned short* __restrict__ A, const unsigned short* __restrict__ Bt,
    unsigned short* As, unsigned short* Bs, const int m0, const int n0,
    f32x4 acc[4][4]) {
  const int t = threadIdx.x, w = t >> 6, l = t & 63;
  const int lr = l & 15, lg = l >> 4;
  const int wr = w >> 1, wc = w & 1;

  const unsigned short* asrc[4];
  const unsigned short* bsrc[4];
  unsigned short* adst[4];
  unsigned short* bdst[4];
  #pragma unroll
  for (int i = 0; i < 4; ++i) {
    const int p = (w * 4 + i) * 64 + l, r = p >> 3, c = p & 7;
    const int cs = c ^ (r & 7);
    asrc[i] = A + (size_t)(m0 + r) * 1024 + cs * 8;
    bsrc[i] = Bt + (size_t)(n0 + r) * 1024 + cs * 8;
    adst[i] = &As[(w * 4 + i) * 512];
    bdst[i] = &Bs[(w * 4 + i) * 512];
  }

  int offA[2][4], offB[2][4];
  #pragma unroll
  for (int ks = 0; ks < 2; ++ks)
    #pragma unroll
    for (int mt = 0; mt < 4; ++mt) {
      offA[ks][mt] = (wr * 64 + mt * 16 + lr) * 64 + ((ks * 4 + lg) ^ (lr & 7)) * 8;
      offB[ks][mt] = (wc * 64 + mt * 16 + lr) * 64 + ((ks * 4 + lg) ^ (lr & 7)) * 8;
    }

  for (int k0 = 0; k0 < 16; ++k0) {
    #pragma unroll
    for (int i = 0; i < 4; ++i) {
      async_ld16(asrc[i], adst[i]);
      async_ld16(bsrc[i], bdst[i]);
      asrc[i] += 64;
      bsrc[i] += 64;
    }
    __syncthreads();
    #pragma unroll
    for (int ks = 0; ks < 2; ++ks) {
      short8 af[4], bf[4];
      #pragma unroll
      for (int mt = 0; mt < 4; ++mt) af[mt] = *(const short8*)&As[offA[ks][mt]];
      #pragma unroll
      for (int nt = 0; nt < 4; ++nt) bf[nt] = *(const short8*)&Bs[offB[ks][nt]];
      #pragma unroll
      for (int mt = 0; mt < 4; ++mt)
        #pragma unroll
        for (int nt = 0; nt < 4; ++nt)
          acc[mt][nt] = SWAP
              ? __builtin_amdgcn_mfma_f32_16x16x32_bf16(bf[nt], af[mt], acc[mt][nt], 0, 0, 0)
              : __builtin_amdgcn_mfma_f32_16x16x32_bf16(af[mt], bf[nt], acc[mt][nt], 0, 0, 0);
    }
    __syncthreads();
  }
}

// ---------------------------------------------------------------------------
// Fused QKV GEMM.  which = blockIdx.y>>3 (0=q 1=k 2=v).
// q/k: SWAP core -> ushort4 stores into (bh,s,d); q scaled 0.125*log2e.
// v:   normal core -> ushort4 stores into (bh,d,s) (validated path).
// ---------------------------------------------------------------------------
__global__ __launch_bounds__(256) void gemm_qkv(
    const unsigned short* __restrict__ A, const unsigned short* __restrict__ wt_all,
    const float* __restrict__ bq, const float* __restrict__ bk,
    const float* __restrict__ bv, unsigned short* __restrict__ q_ws,
    unsigned short* __restrict__ k_ws, unsigned short* __restrict__ vt_ws) {
  __shared__ __align__(16) unsigned short As[128 * 64];
  __shared__ __align__(16) unsigned short Bs[128 * 64];
  const int which = blockIdx.y >> 3;
  const int m0 = blockIdx.x * 128, n0 = (blockIdx.y & 7) * 128;
  const unsigned short* Bt = wt_all + (size_t)which * 1048576;

  const int t = threadIdx.x, w = t >> 6, l = t & 63;
  const int lr = l & 15, lg = l >> 4;
  const int wr = w >> 1, wc = w & 1;
  const int mbase = m0 + wr * 64, nbase = n0 + wc * 64;

  f32x4 acc[4][4];
  #pragma unroll
  for (int mt = 0; mt < 4; ++mt)
    #pragma unroll
    for (int nt = 0; nt < 4; ++nt) acc[mt][nt] = (f32x4){0.f, 0.f, 0.f, 0.f};

  if (which == 2) {
    gemm_core<0>(A, Bt, As, Bs, m0, n0, acc);
    #pragma unroll
    for (int mt = 0; mt < 4; ++mt) {
      const int m4 = mbase + mt * 16 + lg * 4;
      const int b = m4 >> 10, s = m4 & 1023;
      #pragma unroll
      for (int nt = 0; nt < 4; ++nt) {
        const int n = nbase + nt * 16 + lr, h = n >> 6, d = n & 63;
        const float bvv = bv[n];
        ushort4 o;
        o.x = f2bf(acc[mt][nt][0] + bvv);
        o.y = f2bf(acc[mt][nt][1] + bvv);
        o.z = f2bf(acc[mt][nt][2] + bvv);
        o.w = f2bf(acc[mt][nt][3] + bvv);
        *(ushort4*)&vt_ws[(size_t)(b * 16 + h) * 65536 + (size_t)d * 1024 + s] = o;
      }
    }
  } else {
    gemm_core<1>(A, Bt, As, Bs, m0, n0, acc);
    unsigned short* dst = (which == 0) ? q_ws : k_ws;
    const float* bias = (which == 0) ? bq : bk;
    const float scale = (which == 0) ? 0.18033688011f : 1.0f;  // 0.125*log2e
    #pragma unroll
    for (int nt = 0; nt < 4; ++nt) {
      const int n4 = nbase + nt * 16 + lg * 4;
      const int h = n4 >> 6, d = n4 & 63;
      const float4 b4 = *(const float4*)&bias[n4];
      #pragma unroll
      for (int mt = 0; mt < 4; ++mt) {
        const int m = mbase + mt * 16 + lr;
        const int b = m >> 10, s = m & 1023;
        ushort4 o;
        o.x = f2bf((acc[mt][nt][0] + b4.x) * scale);
        o.y = f2bf((acc[mt][nt][1] + b4.y) * scale);
        o.z = f2bf((acc[mt][nt][2] + b4.z) * scale);
        o.w = f2bf((acc[mt][nt][3] + b4.w) * scale);
        *(ushort4*)&dst[(size_t)(b * 16 + h) * 65536 + s * 64 + d] = o;
      }
    }
  }
}

// ---------------------------------------------------------------------------
// Output projection GEMM (fp32 out, SWAP core -> float4 stores).
// ---------------------------------------------------------------------------
__global__ __launch_bounds__(256) void gemm_out(
    const unsigned short* __restrict__ A, const unsigned short* __restrict__ Bt,
    const float* __restrict__ bias, float* __restrict__ C) {
  __shared__ __align__(16) unsigned short As[128 * 64];
  __shared__ __align__(16) unsigned short Bs[128 * 64];
  const int m0 = blockIdx.x * 128, n0 = blockIdx.y * 128;
  f32x4 acc[4][4];
  #pragma unroll
  for (int mt = 0; mt < 4; ++mt)
    #pragma unroll
    for (int nt = 0; nt < 4; ++nt) acc[mt][nt] = (f32x4){0.f, 0.f, 0.f, 0.f};
  gemm_core<1>(A, Bt, As, Bs, m0, n0, acc);

  const int t = threadIdx.x, w = t >> 6, l = t & 63;
  const int lr = l & 15, lg = l >> 4;
  const int wr = w >> 1, wc = w & 1;
  const int mbase = m0 + wr * 64, nbase = n0 + wc * 64;
  #pragma unroll
  for (int nt = 0; nt < 4; ++nt) {
    const int n4 = nbase + nt * 16 + lg * 4;
    const float4 b4 = *(const float4*)&bias[n4];
    #pragma unroll
    for (int mt = 0; mt < 4; ++mt) {
      const int m = mbase + mt * 16 + lr;
      float4 o;
      o.x = acc[mt][nt][0] + b4.x;
      o.y = acc[mt][nt][1] + b4.y;
      o.z = acc[mt][nt][2] + b4.z;
      o.w = acc[mt][nt][3] + b4.w;
      *(float4*)&C[(size_t)m * 1024 + n4] = o;
    }
  }
}

// ---------------------------------------------------------------------------
// MFMA flash attention v3: Q in regs, K dbuf, V single-buf (counted vmcnt),
// exp2 softmax (log2e pre-folded), setprio MFMA clusters, defer-max.
// Block 256 thr (4 waves), 64 q rows (16/wave); K/V tiles of 64.
// LDS 36.8 KB -> 4 blocks/CU.
// ---------------------------------------------------------------------------
__global__ __launch_bounds__(256) void attn_mfma(
    const unsigned short* __restrict__ q_ws, const unsigned short* __restrict__ k_ws,
    const unsigned short* __restrict__ vt_ws, const float* __restrict__ gate_ws,
    const float* __restrict__ btab, unsigned short* __restrict__ ctx) {
  __shared__ __align__(16) unsigned short Ks[2][64 * 64];  // 16 KB
  __shared__ __align__(16) unsigned short Vts[64 * 64];    // 8 KB
  __shared__ __align__(16) unsigned short Ps[4 * 1024];    // 8 KB (2KB/wave)
  __shared__ __align__(16) float biasl[1088];              // 4.25 KB
  __shared__ float gates[64];
  __shared__ float scl[64];

  const int t = threadIdx.x, w = t >> 6, l = t & 63;
  const int lr = l & 15, lg = l >> 4;
  const int bh = blockIdx.x, h = bh & 15, b = bh >> 4;
  const int q0 = blockIdx.y * 64;
  const size_t hb = (size_t)bh * 65536;

  // --- Q fragments direct from global (q pre-scaled by 0.125*log2e) -------
  short8 qf[2];
  #pragma unroll
  for (int ks = 0; ks < 2; ++ks)
    qf[ks] = *(const short8*)(q_ws + hb + (size_t)(q0 + w * 16 + lr) * 64 +
                              (ks * 4 + lg) * 8);

  // --- stage K tile 0 (src-swizzled) --------------------------------------
  #pragma unroll
  for (int i = 0; i < 2; ++i) {
    const int p = (w * 2 + i) * 64 + l, r = p >> 3, c = p & 7;
    const int cs = c ^ (r & 7);
    async_ld16(k_ws + hb + (size_t)r * 64 + cs * 8, &Ks[0][(w * 2 + i) * 512]);
  }
  // --- bias slice + gates --------------------------------------------------
  {
    const float* bt = btab + h * 2048 + (960 - q0);
    for (int u = t * 4; u < 1088; u += 1024)
      *(float4*)&biasl[u] = *(const float4*)&bt[u];
  }
  if (t < 64) gates[t] = gate_ws[bh * 1024 + q0 + t];
  asm volatile("s_waitcnt vmcnt(0) lgkmcnt(0)" ::: "memory");
  __builtin_amdgcn_s_barrier();
  __builtin_amdgcn_sched_barrier(0);

  // --- per-lane offsets ----------------------------------------------------
  int pwoff[4], proff[2], offF[2][4];
  #pragma unroll
  for (int nt = 0; nt < 4; ++nt)
    pwoff[nt] = w * 2048 + ((lr * 128 + nt * 32 + lg * 8) ^ ((lr & 7) << 4));
  #pragma unroll
  for (int ks = 0; ks < 2; ++ks) {
    proff[ks] = w * 2048 + ((lr * 128 + ks * 64 + lg * 16) ^ ((lr & 7) << 4));
    #pragma unroll
    for (int nt = 0; nt < 4; ++nt)
      offF[ks][nt] = (nt * 16 + lr) * 64 + ((ks * 4 + lg) ^ (lr & 7)) * 8;
  }

  float mcur = -1e30f, lsum = 0.f;
  f32x4 acc_o[4];
  #pragma unroll
  for (int dt = 0; dt < 4; ++dt) acc_o[dt] = (f32x4){0.f, 0.f, 0.f, 0.f};
  const float gtl = gates[w * 16 + lr] * 1.44269504f;  // gate * log2e
  const int ub = 63 - w * 16 - lr;
  char* Pb = (char*)Ps;

  int pcur = 0;
  for (int kt = 0; kt < 16; ++kt) {
    // issue V(kt) then K(kt+1)  (V buf WAR-safe: prev PV reads done pre-barrier)
    #pragma unroll
    for (int i = 0; i < 2; ++i) {
      const int p = (w * 2 + i) * 64 + l, r = p >> 3, c = p & 7;
      const int cs = c ^ (r & 7);
      async_ld16(vt_ws + hb + (size_t)r * 1024 + kt * 64 + cs * 8,
                 &Vts[(w * 2 + i) * 512]);
    }
    if (kt < 15) {
      #pragma unroll
      for (int i = 0; i < 2; ++i) {
        const int p = (w * 2 + i) * 64 + l, r = p >> 3, c = p & 7;
        const int cs = c ^ (r & 7);
        async_ld16(k_ws + hb + (size_t)(kt + 1) * 4096 + (size_t)r * 64 + cs * 8,
                   &Ks[pcur ^ 1][(w * 2 + i) * 512]);
      }
    }

    // ---- QK^T swapped: accs[nt][i] = S^T[k=nt*16+lg*4+i][q=lr] (log2 units)
    f32x4 accs[4];
    #pragma unroll
    for (int nt = 0; nt < 4; ++nt) accs[nt] = (f32x4){0.f, 0.f, 0.f, 0.f};
    __builtin_amdgcn_s_setprio(1);
    #pragma unroll
    for (int ks = 0; ks < 2; ++ks) {
      #pragma unroll
      for (int nt = 0; nt < 4; ++nt) {
        const short8 kf = *(const short8*)&Ks[pcur][offF[ks][nt]];
        accs[nt] = __builtin_amdgcn_mfma_f32_16x16x32_bf16(kf, qf[ks], accs[nt], 0, 0, 0);
      }
    }
    __builtin_amdgcn_s_setprio(0);

    // ---- bias + per-lane row max ----------------------------------------
    const int bb = kt * 64 + ub + lg * 4;
    float tm = -1e30f;
    #pragma unroll
    for (int nt = 0; nt < 4; ++nt) {
      #pragma unroll
      for (int i = 0; i < 4; ++i) {
        const float sv = accs[nt][i] + gtl * biasl[bb + nt * 16 + i];
        accs[nt][i] = sv;
      }
      tm = fmaxf(fmaxf(tm, fmaxf(accs[nt][0], accs[nt][1])),
                 fmaxf(accs[nt][2], accs[nt][3]));
    }
    tm = fmaxf(tm, __shfl_xor(tm, 16));
    tm = fmaxf(tm, __shfl_xor(tm, 32));

    const int skip = __all(tm <= mcur + 11.5f);  // defer-max (log2 units)
    float sc = 1.0f;
    if (!skip) {
      const float mn = fmaxf(mcur, tm);
      sc = EXP2(mcur - mn);
      mcur = mn;
      if (lg == 0) scl[w * 16 + lr] = sc;
    }

    // ---- p = exp2(sv - mcur), pack bf16, write P, row sum ----------------
    float ps = 0.f;
    #pragma unroll
    for (int nt = 0; nt < 4; ++nt) {
      const float p0 = EXP2(accs[nt][0] - mcur);
      const float p1 = EXP2(accs[nt][1] - mcur);
      const float p2 = EXP2(accs[nt][2] - mcur);
      const float p3 = EXP2(accs[nt][3] - mcur);
      ps += (p0 + p1) + (p2 + p3);
      short4 pk;
      pk.x = (short)f2bf(p0); pk.y = (short)f2bf(p1);
      pk.z = (short)f2bf(p2); pk.w = (short)f2bf(p3);
      *(short4*)(Pb + pwoff[nt]) = pk;
    }
    ps += __shfl_xor(ps, 16);
    ps += __shfl_xor(ps, 32);
    lsum = skip ? (lsum + ps) : (lsum * sc + ps);

    // ---- barrier B: V landed (K(kt+1) still in flight), P/scl visible ----
    if (kt < 15) {
      asm volatile("s_waitcnt vmcnt(2) lgkmcnt(0)" ::: "memory");
    } else {
      asm volatile("s_waitcnt vmcnt(0) lgkmcnt(0)" ::: "memory");
    }
    __builtin_amdgcn_s_barrier();
    __builtin_amdgcn_sched_barrier(0);

    // ---- rescale acc_o (only when max moved) -----------------------------
    if (!skip) {
      const float s0 = scl[w * 16 + lg * 4 + 0];
      const float s1 = scl[w * 16 + lg * 4 + 1];
      const float s2 = scl[w * 16 + lg * 4 + 2];
      const float s3 = scl[w * 16 + lg * 4 + 3];
      #pragma unroll
      for (int dt = 0; dt < 4; ++dt) {
        acc_o[dt][0] *= s0; acc_o[dt][1] *= s1;
        acc_o[dt][2] *= s2; acc_o[dt][3] *= s3;
      }
    }

    // ---- PV: O[q][d] += P[q][k] V[k][d] ----------------------------------
    __builtin_amdgcn_s_setprio(1);
    #pragma unroll
    for (int ks = 0; ks < 2; ++ks) {
      const short8 pf = *(const short8*)(Pb + proff[ks]);
      #pragma unroll
      for (int dt = 0; dt < 4; ++dt) {
        const short8 vf = *(const short8*)&Vts[offF[ks][dt]];
        acc_o[dt] = __builtin_amdgcn_mfma_f32_16x16x32_bf16(pf, vf, acc_o[dt], 0, 0, 0);
      }
    }
    __builtin_amdgcn_s_setprio(0);

    // ---- barrier A: K(kt+1) landed; all waves' PV reads done -------------
    asm volatile("s_waitcnt vmcnt(0)" ::: "memory");
    __builtin_amdgcn_s_barrier();
    __builtin_amdgcn_sched_barrier(0);
    pcur ^= 1;
  }

  // ---- epilogue -----------------------------------------------------------
  if (lg == 0) scl[w * 16 + lr] = 1.0f / lsum;
  asm volatile("s_waitcnt lgkmcnt(0)" ::: "memory");
  __builtin_amdgcn_sched_barrier(0);
  float inv[4];
  #pragma unroll
  for (int i = 0; i < 4; ++i) inv[i] = scl[w * 16 + lg * 4 + i];
  #pragma unroll
  for (int i = 0; i < 4; ++i) {
    const int q = q0 + w * 16 + lg * 4 + i;
    const size_t rowoff = ((size_t)(b * 1024 + q) * 16 + h) * 64;
    #pragma unroll
    for (int dt = 0; dt < 4; ++dt)
      ctx[rowoff + dt * 16 + lr] = f2bf(acc_o[dt][i] * inv[i]);
  }
}

// ---------------------------------------------------------------------------
extern "C" void kernel_launch(void* const* d_in, const int* in_sizes, int n_in,
                              void* d_out, int out_size, void* d_ws, size_t ws_size,
                              hipStream_t stream) {
  const float* x    = (const float*)d_in[0];
  const float* Wq   = (const float*)d_in[1];
  const float* bq   = (const float*)d_in[2];
  const float* Wk   = (const float*)d_in[3];
  const float* bk   = (const float*)d_in[4];
  const float* Wv   = (const float*)d_in[5];
  const float* bv   = (const float*)d_in[6];
  const float* Wo   = (const float*)d_in[7];
  const float* bo   = (const float*)d_in[8];
  const float* rel  = (const float*)d_in[9];
  const float* gw   = (const float*)d_in[10];
  const float* gb   = (const float*)d_in[11];
  const float* gcst = (const float*)d_in[12];
  float* out = (float*)d_out;

  char* ws = (char*)d_ws;
  unsigned short* x_bf   = (unsigned short*)(ws);
  unsigned short* wt_all = (unsigned short*)(ws + 16777216);
  unsigned short* q_ws   = (unsigned short*)(ws + 25165824);
  unsigned short* k_ws   = (unsigned short*)(ws + 41943040);
  unsigned short* vt_ws  = (unsigned short*)(ws + 58720256);
  unsigned short* ctx    = (unsigned short*)(ws + 75497472);
  float* gate = (float*)(ws + 92274688);
  float* btab = (float*)(ws + 92798976);

  prep_all <<<dim3(9224),    256, 0, stream>>>(x, gw, gb, gcst, Wq, Wk, Wv, Wo,
                                               rel, x_bf, gate, wt_all, btab);
  gemm_qkv <<<dim3(64, 24),  256, 0, stream>>>(x_bf, wt_all, bq, bk, bv,
                                               q_ws, k_ws, vt_ws);
  attn_mfma<<<dim3(128, 16), 256, 0, stream>>>(q_ws, k_ws, vt_ws, gate, btab, ctx);
  gemm_out <<<dim3(64, 8),   256, 0, stream>>>(ctx, wt_all + 3 * 1048576, bo, out);
}

// Round 5
// 286.247 us; speedup vs baseline: 7.4359x; 1.0202x over previous
//
#include <hip/hip_runtime.h>
#include <hip/hip_bf16.h>
#include <math.h>

// ---------------------------------------------------------------------------
// WavLM self-attention, bf16-MFMA v4.
//   B=8 S=1024 H=16 D=64 E=1024; q pre-scaled by 0.125*log2(e) (exp2 softmax)
// Round-5 changes vs validated round-4:
//   * attn: 128 q-rows/block, 8 waves (512 thr) -> 3 blocks/CU, 24 waves/CU;
//     halved staging instrs + halved K/V L2 traffic
//   * attn: bias folded into MFMA C-init (no zero-init, no post-FMA)
//   * attn: per-lane partial lsum, reduced once at end (no per-tile shfls)
//   * GEMMs / prep unchanged (validated round-4 code)
// Workspace (bytes): same layout as round-3/4.
// ---------------------------------------------------------------------------

typedef __attribute__((ext_vector_type(8))) short short8;
typedef __attribute__((ext_vector_type(4))) float f32x4;

#define LDSP(p) ((__attribute__((address_space(3))) void*)(p))
#define GLBP(p) ((const __attribute__((address_space(1))) void*)(p))

__device__ __forceinline__ void async_ld16(const void* src, void* dst) {
  __builtin_amdgcn_global_load_lds(GLBP(src), LDSP(dst), 16, 0, 0);
}
__device__ __forceinline__ unsigned short f2bf(float f) {
  __hip_bfloat16 h = __float2bfloat16(f);
  return __builtin_bit_cast(unsigned short, h);
}
#if __has_builtin(__builtin_amdgcn_exp2f)
#define EXP2(x) __builtin_amdgcn_exp2f(x)
#else
#define EXP2(x) exp2f(x)
#endif

// ---------------------------------------------------------------------------
// Fused prep: [0,8192) cvt+gate, [8192,9216) transW x4, [9216,9224) btab.
// (unchanged, validated)
// ---------------------------------------------------------------------------
__global__ __launch_bounds__(256) void prep_all(
    const float* __restrict__ x, const float* __restrict__ gw,
    const float* __restrict__ gb, const float* __restrict__ gcst,
    const float* __restrict__ W0, const float* __restrict__ W1,
    const float* __restrict__ W2, const float* __restrict__ W3,
    const float* __restrict__ rel_embed,
    unsigned short* __restrict__ xb, float* __restrict__ gate_ws,
    unsigned short* __restrict__ Wt_all, float* __restrict__ btab) {
  __shared__ __align__(16) float tile[64][68];
  const int bid = blockIdx.x, t = threadIdx.x;
  if (bid < 8192) {
    float* xr = &tile[0][0];
    const float4 v = *(const float4*)&x[(size_t)bid * 1024 + t * 4];
    *(float4*)&xr[t * 4] = v;
    ushort4 o;
    o.x = f2bf(v.x); o.y = f2bf(v.y); o.z = f2bf(v.z); o.w = f2bf(v.w);
    *(ushort4*)&xb[(size_t)bid * 1024 + t * 4] = o;
    __syncthreads();
    const int h = t >> 4, i = t & 15;
    float pa = 0.f, pb = 0.f;
    #pragma unroll
    for (int j = 0; j < 4; ++j) {
      const int d = i * 4 + j;
      const float xv = xr[h * 64 + d];
      const float* wr = &gw[d * 8];
      pa += xv * (wr[0] + wr[1] + wr[2] + wr[3]);
      pb += xv * (wr[4] + wr[5] + wr[6] + wr[7]);
    }
    #pragma unroll
    for (int msk = 1; msk <= 8; msk <<= 1) {
      pa += __shfl_xor(pa, msk);
      pb += __shfl_xor(pb, msk);
    }
    if (i == 0) {
      const float ba = gb[0] + gb[1] + gb[2] + gb[3];
      const float bb = gb[4] + gb[5] + gb[6] + gb[7];
      const float ga  = 1.f / (1.f + __expf(-(pa + ba)));
      const float gbv = 1.f / (1.f + __expf(-(pb + bb)));
      const float gv  = ga * (gbv * gcst[h] - 1.f) + 2.f;
      const int b = bid >> 10, s = bid & 1023;
      gate_ws[(b * 16 + h) * 1024 + s] = gv;
    }
  } else if (bid < 9216) {
    const int zz = bid - 8192;
    const int z = zz >> 8;
    const float* W = (z == 0) ? W0 : (z == 1) ? W1 : (z == 2) ? W2 : W3;
    unsigned short* Wt = Wt_all + (size_t)z * 1048576;
    const int n0 = (zz & 15) * 64, k0 = ((zz >> 4) & 15) * 64;
    const int c = (t & 15) * 4, r = t >> 4;
    #pragma unroll
    for (int i = 0; i < 4; ++i)
      *(float4*)&tile[r + i * 16][c] =
          *(const float4*)&W[(size_t)(k0 + r + i * 16) * 1024 + n0 + c];
    __syncthreads();
    #pragma unroll
    for (int i = 0; i < 4; ++i) {
      const int n = r + i * 16;
      ushort4 o;
      o.x = f2bf(tile[c + 0][n]); o.y = f2bf(tile[c + 1][n]);
      o.z = f2bf(tile[c + 2][n]); o.w = f2bf(tile[c + 3][n]);
      *(ushort4*)&Wt[(size_t)(n0 + n) * 1024 + k0 + c] = o;
    }
  } else {
    const int idx = (bid - 9216) * 256 + t;
    if (idx < 2047) {
      const int rel = idx - 1023;
      int bucket = (rel > 0) ? 16 : 0;
      const int rp = rel < 0 ? -rel : rel;
      if (rp < 8) {
        bucket += rp;
      } else {
        const double lv = log((double)rp / 8.0) / log(16.0) * 8.0;
        int large = 8 + (int)lv;
        bucket += (large < 15) ? large : 15;
      }
      #pragma unroll
      for (int h = 0; h < 16; ++h)
        btab[h * 2048 + idx] = rel_embed[bucket * 16 + h];
    }
  }
}

// ---------------------------------------------------------------------------
// Shared GEMM core (validated 2-barrier structure, unchanged).
// ---------------------------------------------------------------------------
template <int SWAP>
__device__ __forceinline__ void gemm_core(
    const unsigned short* __restrict__ A, const unsigned short* __restrict__ Bt,
    unsigned short* As, unsigned short* Bs, const int m0, const int n0,
    f32x4 acc[4][4]) {
  const int t = threadIdx.x, w = t >> 6, l = t & 63;
  const int lr = l & 15, lg = l >> 4;
  const int wr = w >> 1, wc = w & 1;

  const unsigned short* asrc[4];
  const unsigned short* bsrc[4];
  unsigned short* adst[4];
  unsigned short* bdst[4];
  #pragma unroll
  for (int i = 0; i < 4; ++i) {
    const int p = (w * 4 + i) * 64 + l, r = p >> 3, c = p & 7;
    const int cs = c ^ (r & 7);
    asrc[i] = A + (size_t)(m0 + r) * 1024 + cs * 8;
    bsrc[i] = Bt + (size_t)(n0 + r) * 1024 + cs * 8;
    adst[i] = &As[(w * 4 + i) * 512];
    bdst[i] = &Bs[(w * 4 + i) * 512];
  }

  int offA[2][4], offB[2][4];
  #pragma unroll
  for (int ks = 0; ks < 2; ++ks)
    #pragma unroll
    for (int mt = 0; mt < 4; ++mt) {
      offA[ks][mt] = (wr * 64 + mt * 16 + lr) * 64 + ((ks * 4 + lg) ^ (lr & 7)) * 8;
      offB[ks][mt] = (wc * 64 + mt * 16 + lr) * 64 + ((ks * 4 + lg) ^ (lr & 7)) * 8;
    }

  for (int k0 = 0; k0 < 16; ++k0) {
    #pragma unroll
    for (int i = 0; i < 4; ++i) {
      async_ld16(asrc[i], adst[i]);
      async_ld16(bsrc[i], bdst[i]);
      asrc[i] += 64;
      bsrc[i] += 64;
    }
    __syncthreads();
    #pragma unroll
    for (int ks = 0; ks < 2; ++ks) {
      short8 af[4], bf[4];
      #pragma unroll
      for (int mt = 0; mt < 4; ++mt) af[mt] = *(const short8*)&As[offA[ks][mt]];
      #pragma unroll
      for (int nt = 0; nt < 4; ++nt) bf[nt] = *(const short8*)&Bs[offB[ks][nt]];
      #pragma unroll
      for (int mt = 0; mt < 4; ++mt)
        #pragma unroll
        for (int nt = 0; nt < 4; ++nt)
          acc[mt][nt] = SWAP
              ? __builtin_amdgcn_mfma_f32_16x16x32_bf16(bf[nt], af[mt], acc[mt][nt], 0, 0, 0)
              : __builtin_amdgcn_mfma_f32_16x16x32_bf16(af[mt], bf[nt], acc[mt][nt], 0, 0, 0);
    }
    __syncthreads();
  }
}

// ---------------------------------------------------------------------------
// Fused QKV GEMM (unchanged, validated).
// ---------------------------------------------------------------------------
__global__ __launch_bounds__(256) void gemm_qkv(
    const unsigned short* __restrict__ A, const unsigned short* __restrict__ wt_all,
    const float* __restrict__ bq, const float* __restrict__ bk,
    const float* __restrict__ bv, unsigned short* __restrict__ q_ws,
    unsigned short* __restrict__ k_ws, unsigned short* __restrict__ vt_ws) {
  __shared__ __align__(16) unsigned short As[128 * 64];
  __shared__ __align__(16) unsigned short Bs[128 * 64];
  const int which = blockIdx.y >> 3;
  const int m0 = blockIdx.x * 128, n0 = (blockIdx.y & 7) * 128;
  const unsigned short* Bt = wt_all + (size_t)which * 1048576;

  const int t = threadIdx.x, w = t >> 6, l = t & 63;
  const int lr = l & 15, lg = l >> 4;
  const int wr = w >> 1, wc = w & 1;
  const int mbase = m0 + wr * 64, nbase = n0 + wc * 64;

  f32x4 acc[4][4];
  #pragma unroll
  for (int mt = 0; mt < 4; ++mt)
    #pragma unroll
    for (int nt = 0; nt < 4; ++nt) acc[mt][nt] = (f32x4){0.f, 0.f, 0.f, 0.f};

  if (which == 2) {
    gemm_core<0>(A, Bt, As, Bs, m0, n0, acc);
    #pragma unroll
    for (int mt = 0; mt < 4; ++mt) {
      const int m4 = mbase + mt * 16 + lg * 4;
      const int b = m4 >> 10, s = m4 & 1023;
      #pragma unroll
      for (int nt = 0; nt < 4; ++nt) {
        const int n = nbase + nt * 16 + lr, h = n >> 6, d = n & 63;
        const float bvv = bv[n];
        ushort4 o;
        o.x = f2bf(acc[mt][nt][0] + bvv);
        o.y = f2bf(acc[mt][nt][1] + bvv);
        o.z = f2bf(acc[mt][nt][2] + bvv);
        o.w = f2bf(acc[mt][nt][3] + bvv);
        *(ushort4*)&vt_ws[(size_t)(b * 16 + h) * 65536 + (size_t)d * 1024 + s] = o;
      }
    }
  } else {
    gemm_core<1>(A, Bt, As, Bs, m0, n0, acc);
    unsigned short* dst = (which == 0) ? q_ws : k_ws;
    const float* bias = (which == 0) ? bq : bk;
    const float scale = (which == 0) ? 0.18033688011f : 1.0f;  // 0.125*log2e
    #pragma unroll
    for (int nt = 0; nt < 4; ++nt) {
      const int n4 = nbase + nt * 16 + lg * 4;
      const int h = n4 >> 6, d = n4 & 63;
      const float4 b4 = *(const float4*)&bias[n4];
      #pragma unroll
      for (int mt = 0; mt < 4; ++mt) {
        const int m = mbase + mt * 16 + lr;
        const int b = m >> 10, s = m & 1023;
        ushort4 o;
        o.x = f2bf((acc[mt][nt][0] + b4.x) * scale);
        o.y = f2bf((acc[mt][nt][1] + b4.y) * scale);
        o.z = f2bf((acc[mt][nt][2] + b4.z) * scale);
        o.w = f2bf((acc[mt][nt][3] + b4.w) * scale);
        *(ushort4*)&dst[(size_t)(b * 16 + h) * 65536 + s * 64 + d] = o;
      }
    }
  }
}

// ---------------------------------------------------------------------------
// Output projection GEMM (unchanged, validated).
// ---------------------------------------------------------------------------
__global__ __launch_bounds__(256) void gemm_out(
    const unsigned short* __restrict__ A, const unsigned short* __restrict__ Bt,
    const float* __restrict__ bias, float* __restrict__ C) {
  __shared__ __align__(16) unsigned short As[128 * 64];
  __shared__ __align__(16) unsigned short Bs[128 * 64];
  const int m0 = blockIdx.x * 128, n0 = blockIdx.y * 128;
  f32x4 acc[4][4];
  #pragma unroll
  for (int mt = 0; mt < 4; ++mt)
    #pragma unroll
    for (int nt = 0; nt < 4; ++nt) acc[mt][nt] = (f32x4){0.f, 0.f, 0.f, 0.f};
  gemm_core<1>(A, Bt, As, Bs, m0, n0, acc);

  const int t = threadIdx.x, w = t >> 6, l = t & 63;
  const int lr = l & 15, lg = l >> 4;
  const int wr = w >> 1, wc = w & 1;
  const int mbase = m0 + wr * 64, nbase = n0 + wc * 64;
  #pragma unroll
  for (int nt = 0; nt < 4; ++nt) {
    const int n4 = nbase + nt * 16 + lg * 4;
    const float4 b4 = *(const float4*)&bias[n4];
    #pragma unroll
    for (int mt = 0; mt < 4; ++mt) {
      const int m = mbase + mt * 16 + lr;
      float4 o;
      o.x = acc[mt][nt][0] + b4.x;
      o.y = acc[mt][nt][1] + b4.y;
      o.z = acc[mt][nt][2] + b4.z;
      o.w = acc[mt][nt][3] + b4.w;
      *(float4*)&C[(size_t)m * 1024 + n4] = o;
    }
  }
}

// ---------------------------------------------------------------------------
// MFMA flash attention v4: 128 q rows/block, 8 waves (512 thr).
// Q in regs, K dbuf, V single-buf (counted vmcnt), bias as MFMA C-init,
// exp2 softmax, deferred lsum reduce, defer-max, setprio MFMA clusters.
// LDS ~46.9 KB -> 3 blocks/CU (24 waves/CU).
// ---------------------------------------------------------------------------
__global__ __launch_bounds__(512) void attn_mfma(
    const unsigned short* __restrict__ q_ws, const unsigned short* __restrict__ k_ws,
    const unsigned short* __restrict__ vt_ws, const float* __restrict__ gate_ws,
    const float* __restrict__ btab, unsigned short* __restrict__ ctx) {
  __shared__ __align__(16) unsigned short Ks[2][64 * 64];  // 16 KB
  __shared__ __align__(16) unsigned short Vts[64 * 64];    // 8 KB
  __shared__ __align__(16) unsigned short Ps[8 * 1024];    // 16 KB (2KB/wave)
  __shared__ __align__(16) float biasl[1216];              // 4.75 KB
  __shared__ float gates[128];
  __shared__ float scl[128];

  const int t = threadIdx.x, w = t >> 6, l = t & 63;
  const int lr = l & 15, lg = l >> 4;
  const int bh = blockIdx.x, h = bh & 15, b = bh >> 4;
  const int q0 = blockIdx.y * 128;
  const size_t hb = (size_t)bh * 65536;

  // --- Q fragments direct from global (q pre-scaled by 0.125*log2e) -------
  short8 qf[2];
  #pragma unroll
  for (int ks = 0; ks < 2; ++ks)
    qf[ks] = *(const short8*)(q_ws + hb + (size_t)(q0 + w * 16 + lr) * 64 +
                              (ks * 4 + lg) * 8);

  // --- stage K tile 0 (src-swizzled); 512 thr -> 1 load covers 8KB --------
  {
    const int p = t, r = p >> 3, c = p & 7;
    const int cs = c ^ (r & 7);
    async_ld16(k_ws + hb + (size_t)r * 64 + cs * 8, &Ks[0][w * 512]);
  }
  // --- bias slice + gates --------------------------------------------------
  // biasl[u] = btab[h][ (896 - q0) + u ], covers rel in [-q0-127, 1023-q0]
  {
    const float* bt = btab + h * 2048 + (896 - q0);
    const int u = t * 4;
    if (u < 1216) *(float4*)&biasl[u] = *(const float4*)&bt[u];
  }
  if (t < 128) gates[t] = gate_ws[bh * 1024 + q0 + t];
  asm volatile("s_waitcnt vmcnt(0) lgkmcnt(0)" ::: "memory");
  __builtin_amdgcn_s_barrier();
  __builtin_amdgcn_sched_barrier(0);

  // --- per-lane offsets ----------------------------------------------------
  int pwoff[4], proff[2], offF[2][4];
  #pragma unroll
  for (int nt = 0; nt < 4; ++nt)
    pwoff[nt] = w * 2048 + ((lr * 128 + nt * 32 + lg * 8) ^ ((lr & 7) << 4));
  #pragma unroll
  for (int ks = 0; ks < 2; ++ks) {
    proff[ks] = w * 2048 + ((lr * 128 + ks * 64 + lg * 16) ^ ((lr & 7) << 4));
    #pragma unroll
    for (int nt = 0; nt < 4; ++nt)
      offF[ks][nt] = (nt * 16 + lr) * 64 + ((ks * 4 + lg) ^ (lr & 7)) * 8;
  }

  float mcur = -1e30f, lsum = 0.f;   // lsum: per-lane partial (reduced at end)
  f32x4 acc_o[4];
  #pragma unroll
  for (int dt = 0; dt < 4; ++dt) acc_o[dt] = (f32x4){0.f, 0.f, 0.f, 0.f};
  const float gtl = gates[w * 16 + lr] * 1.44269504f;  // gate * log2e
  const int ub = 127 - w * 16 - lr;
  char* Pb = (char*)Ps;

  int pcur = 0;
  for (int kt = 0; kt < 16; ++kt) {
    // issue V(kt) then K(kt+1) (V buf WAR-safe: prev PV reads done pre-barrier)
    {
      const int p = t, r = p >> 3, c = p & 7;
      const int cs = c ^ (r & 7);
      async_ld16(vt_ws + hb + (size_t)r * 1024 + kt * 64 + cs * 8, &Vts[w * 512]);
      if (kt < 15)
        async_ld16(k_ws + hb + (size_t)(kt + 1) * 4096 + (size_t)r * 64 + cs * 8,
                   &Ks[pcur ^ 1][w * 512]);
    }

    // ---- C-init = gate*bias (ds_reads hide under MFMA issue) -------------
    const int bb = kt * 64 + ub + lg * 4;
    f32x4 accs[4];
    #pragma unroll
    for (int nt = 0; nt < 4; ++nt) {
      accs[nt][0] = gtl * biasl[bb + nt * 16 + 0];
      accs[nt][1] = gtl * biasl[bb + nt * 16 + 1];
      accs[nt][2] = gtl * biasl[bb + nt * 16 + 2];
      accs[nt][3] = gtl * biasl[bb + nt * 16 + 3];
    }

    // ---- QK^T swapped: accs[nt][i] += S^T[k=nt*16+lg*4+i][q=lr] ----------
    __builtin_amdgcn_s_setprio(1);
    #pragma unroll
    for (int ks = 0; ks < 2; ++ks) {
      #pragma unroll
      for (int nt = 0; nt < 4; ++nt) {
        const short8 kf = *(const short8*)&Ks[pcur][offF[ks][nt]];
        accs[nt] = __builtin_amdgcn_mfma_f32_16x16x32_bf16(kf, qf[ks], accs[nt], 0, 0, 0);
      }
    }
    __builtin_amdgcn_s_setprio(0);

    // ---- per-lane row max ------------------------------------------------
    float tm = -1e30f;
    #pragma unroll
    for (int nt = 0; nt < 4; ++nt)
      tm = fmaxf(fmaxf(tm, fmaxf(accs[nt][0], accs[nt][1])),
                 fmaxf(accs[nt][2], accs[nt][3]));
    tm = fmaxf(tm, __shfl_xor(tm, 16));
    tm = fmaxf(tm, __shfl_xor(tm, 32));

    const int skip = __all(tm <= mcur + 11.5f);  // defer-max (log2 units)
    float sc = 1.0f;
    if (!skip) {
      const float mn = fmaxf(mcur, tm);
      sc = EXP2(mcur - mn);
      mcur = mn;
      if (lg == 0) scl[w * 16 + lr] = sc;
    }

    // ---- p = exp2(sv - mcur), pack bf16, write P, partial row sum --------
    float ps = 0.f;
    #pragma unroll
    for (int nt = 0; nt < 4; ++nt) {
      const float p0 = EXP2(accs[nt][0] - mcur);
      const float p1 = EXP2(accs[nt][1] - mcur);
      const float p2 = EXP2(accs[nt][2] - mcur);
      const float p3 = EXP2(accs[nt][3] - mcur);
      ps += (p0 + p1) + (p2 + p3);
      short4 pk;
      pk.x = (short)f2bf(p0); pk.y = (short)f2bf(p1);
      pk.z = (short)f2bf(p2); pk.w = (short)f2bf(p3);
      *(short4*)(Pb + pwoff[nt]) = pk;
    }
    lsum = skip ? (lsum + ps) : (lsum * sc + ps);

    // ---- barrier B: V landed (K(kt+1) still in flight), P/scl visible ----
    if (kt < 15) {
      asm volatile("s_waitcnt vmcnt(1) lgkmcnt(0)" ::: "memory");
    } else {
      asm volatile("s_waitcnt vmcnt(0) lgkmcnt(0)" ::: "memory");
    }
    __builtin_amdgcn_s_barrier();
    __builtin_amdgcn_sched_barrier(0);

    // ---- rescale acc_o (only when max moved) -----------------------------
    if (!skip) {
      const float s0 = scl[w * 16 + lg * 4 + 0];
      const float s1 = scl[w * 16 + lg * 4 + 1];
      const float s2 = scl[w * 16 + lg * 4 + 2];
      const float s3 = scl[w * 16 + lg * 4 + 3];
      #pragma unroll
      for (int dt = 0; dt < 4; ++dt) {
        acc_o[dt][0] *= s0; acc_o[dt][1] *= s1;
        acc_o[dt][2] *= s2; acc_o[dt][3] *= s3;
      }
    }

    // ---- PV: O[q][d] += P[q][k] V[k][d] ----------------------------------
    __builtin_amdgcn_s_setprio(1);
    #pragma unroll
    for (int ks = 0; ks < 2; ++ks) {
      const short8 pf = *(const short8*)(Pb + proff[ks]);
      #pragma unroll
      for (int dt = 0; dt < 4; ++dt) {
        const short8 vf = *(const short8*)&Vts[offF[ks][dt]];
        acc_o[dt] = __builtin_amdgcn_mfma_f32_16x16x32_bf16(pf, vf, acc_o[dt], 0, 0, 0);
      }
    }
    __builtin_amdgcn_s_setprio(0);

    // ---- barrier A: K(kt+1) landed; all waves' PV reads done -------------
    asm volatile("s_waitcnt vmcnt(0)" ::: "memory");
    __builtin_amdgcn_s_barrier();
    __builtin_amdgcn_sched_barrier(0);
    pcur ^= 1;
  }

  // ---- epilogue: reduce partial lsum across the 4 lanes of each q-row ----
  lsum += __shfl_xor(lsum, 16);
  lsum += __shfl_xor(lsum, 32);
  if (lg == 0) scl[w * 16 + lr] = 1.0f / lsum;
  asm volatile("s_waitcnt lgkmcnt(0)" ::: "memory");
  __builtin_amdgcn_s_barrier();   // scl visible block-wide (cheap, once)
  float inv[4];
  #pragma unroll
  for (int i = 0; i < 4; ++i) inv[i] = scl[w * 16 + lg * 4 + i];
  #pragma unroll
  for (int i = 0; i < 4; ++i) {
    const int q = q0 + w * 16 + lg * 4 + i;
    const size_t rowoff = ((size_t)(b * 1024 + q) * 16 + h) * 64;
    #pragma unroll
    for (int dt = 0; dt < 4; ++dt)
      ctx[rowoff + dt * 16 + lr] = f2bf(acc_o[dt][i] * inv[i]);
  }
}

// ---------------------------------------------------------------------------
extern "C" void kernel_launch(void* const* d_in, const int* in_sizes, int n_in,
                              void* d_out, int out_size, void* d_ws, size_t ws_size,
                              hipStream_t stream) {
  const float* x    = (const float*)d_in[0];
  const float* Wq   = (const float*)d_in[1];
  const float* bq   = (const float*)d_in[2];
  const float* Wk   = (const float*)d_in[3];
  const float* bk   = (const float*)d_in[4];
  const float* Wv   = (const float*)d_in[5];
  const float* bv   = (const float*)d_in[6];
  const float* Wo   = (const float*)d_in[7];
  const float* bo   = (const float*)d_in[8];
  const float* rel  = (const float*)d_in[9];
  const float* gw   = (const float*)d_in[10];
  const float* gb   = (const float*)d_in[11];
  const float* gcst = (const float*)d_in[12];
  float* out = (float*)d_out;

  char* ws = (char*)d_ws;
  unsigned short* x_bf   = (unsigned short*)(ws);
  unsigned short* wt_all = (unsigned short*)(ws + 16777216);
  unsigned short* q_ws   = (unsigned short*)(ws + 25165824);
  unsigned short* k_ws   = (unsigned short*)(ws + 41943040);
  unsigned short* vt_ws  = (unsigned short*)(ws + 58720256);
  unsigned short* ctx    = (unsigned short*)(ws + 75497472);
  float* gate = (float*)(ws + 92274688);
  float* btab = (float*)(ws + 92798976);

  prep_all <<<dim3(9224),   256, 0, stream>>>(x, gw, gb, gcst, Wq, Wk, Wv, Wo,
                                              rel, x_bf, gate, wt_all, btab);
  gemm_qkv <<<dim3(64, 24), 256, 0, stream>>>(x_bf, wt_all, bq, bk, bv,
                                              q_ws, k_ws, vt_ws);
  attn_mfma<<<dim3(128, 8), 512, 0, stream>>>(q_ws, k_ws, vt_ws, gate, btab, ctx);
  gemm_out <<<dim3(64, 8),  256, 0, stream>>>(ctx, wt_all + 3 * 1048576, bo, out);
}